// Round 1
// baseline (27394.534 us; speedup 1.0000x reference)
//
#include <hip/hip_runtime.h>
#include <cstdint>
#include <cstddef>

// ---------------------------------------------------------------------------
// Problem constants
// ---------------------------------------------------------------------------
#define B_SZ 32
#define T_SZ 1024
#define DIN  80
#define H3   256   // encoder output dim
#define FEAT 768   // 3 * H3
#define G4   1024  // 4 * H (LSTM gates)
#define HH   256   // LSTM hidden

typedef __attribute__((ext_vector_type(8))) short short8;   // 8 x bf16 (4 VGPRs)
typedef __attribute__((ext_vector_type(4))) float f32x4;    // MFMA accumulator

__device__ inline float bf2f(unsigned short u) {
    return __uint_as_float(((unsigned int)u) << 16);
}
__device__ inline unsigned short f2bf(float f) {
    unsigned int u = __float_as_uint(f);
    u += 0x7fffu + ((u >> 16) & 1u);   // RNE
    return (unsigned short)(u >> 16);
}

// ---------------------------------------------------------------------------
// fp32 -> bf16 conversion (grid-stride)
// ---------------------------------------------------------------------------
__global__ void k_cvt(const float* __restrict__ src, unsigned short* __restrict__ dst, int n) {
    int i = blockIdx.x * blockDim.x + threadIdx.x;
    int stride = gridDim.x * blockDim.x;
    for (; i < n; i += stride) dst[i] = f2bf(src[i]);
}

// transpose Whh [1024,256] -> Wt [256,1024] fp32 (one-time, coalesced reads)
__global__ void k_transpose(const float* __restrict__ W, float* __restrict__ Wt) {
    int i = blockIdx.x * 256 + threadIdx.x;   // 262144 total
    int n = i >> 8, k = i & 255;
    Wt[(size_t)k * G4 + n] = W[i];
}

// ---------------------------------------------------------------------------
// stable argsort by descending length (matches jnp.argsort(-lens), stable)
// ---------------------------------------------------------------------------
__global__ void k_order(const int* __restrict__ lens, int* __restrict__ order,
                        int* __restrict__ lens_sorted, float* __restrict__ out_order) {
    int b = threadIdx.x;
    if (b < B_SZ) {
        int lb = lens[b];
        int r = 0;
        for (int j = 0; j < B_SZ; ++j) {
            int lj = lens[j];
            if (lj > lb || (lj == lb && j < b)) ++r;
        }
        order[r] = b;
        lens_sorted[r] = lb;
        out_order[r] = (float)b;   // second tuple output, as float
    }
}

// rowmap for backward direction: rowmap[bs*1024+t] = bs*1024 + clip(len-1-t, 0, 1023)
__global__ void k_rowmap(const int* __restrict__ lens_sorted, int* __restrict__ rowmap) {
    int idx = blockIdx.x * 256 + threadIdx.x;   // 32768 total
    int bs = idx >> 10, t = idx & 1023;
    int len = lens_sorted[bs];
    int src = len - 1 - t;
    src = src < 0 ? 0 : src;
    rowmap[idx] = (bs << 10) + src;
}

// ---------------------------------------------------------------------------
// bf16 MFMA GEMM: C[M,N] = act(A[M,K] @ Bw[N,K]^T + bias1 + bias2), bf16 out.
// A rows optionally gathered through rowmap. Block tile 32(M) x 128(N),
// 4 waves (2x2), each wave 16x64 via 4 accumulators. No LDS (round-0 simple).
// Fragment mapping per guide (m89/m91 verified):
//   A-frag: m = lane&15, k = (lane>>4)*8 + j   (8 contiguous bf16 = 16B load)
//   B-frag: n = lane&15, k = (lane>>4)*8 + j   (weights are [N,K] row-major)
//   D:      col = lane&15, row = (lane>>4)*4 + reg
// ---------------------------------------------------------------------------
__global__ __launch_bounds__(256) void k_gemm(
    const unsigned short* __restrict__ A, const unsigned short* __restrict__ Bw,
    const int* __restrict__ rowmap,
    const float* __restrict__ bias1, const float* __restrict__ bias2,
    unsigned short* __restrict__ C, int M, int N, int K, int relu)
{
    int tid  = threadIdx.x;
    int lane = tid & 63;
    int wave = tid >> 6;
    int waveM = wave >> 1, waveN = wave & 1;
    int l16  = lane & 15;
    int quad = lane >> 4;
    int mBase = blockIdx.x * 32 + waveM * 16;
    int nBase = blockIdx.y * 128 + waveN * 64;

    int mA = mBase + l16;
    int rowA = rowmap ? rowmap[mA] : mA;
    const unsigned short* pA  = A  + (size_t)rowA * K + quad * 8;
    const unsigned short* pB0 = Bw + (size_t)(nBase +  0 + l16) * K + quad * 8;
    const unsigned short* pB1 = Bw + (size_t)(nBase + 16 + l16) * K + quad * 8;
    const unsigned short* pB2 = Bw + (size_t)(nBase + 32 + l16) * K + quad * 8;
    const unsigned short* pB3 = Bw + (size_t)(nBase + 48 + l16) * K + quad * 8;

    const short8 z8 = {0, 0, 0, 0, 0, 0, 0, 0};
    f32x4 acc0 = {0.f, 0.f, 0.f, 0.f};
    f32x4 acc1 = acc0, acc2 = acc0, acc3 = acc0;

    for (int k0 = 0; k0 < K; k0 += 32) {
        bool ok = (k0 + quad * 8) < K;   // K % 8 == 0 for all layers (80,512,768)
        short8 av  = ok ? *(const short8*)(const void*)(pA  + k0) : z8;
        short8 bv0 = ok ? *(const short8*)(const void*)(pB0 + k0) : z8;
        short8 bv1 = ok ? *(const short8*)(const void*)(pB1 + k0) : z8;
        short8 bv2 = ok ? *(const short8*)(const void*)(pB2 + k0) : z8;
        short8 bv3 = ok ? *(const short8*)(const void*)(pB3 + k0) : z8;
        acc0 = __builtin_amdgcn_mfma_f32_16x16x32_bf16(av, bv0, acc0, 0, 0, 0);
        acc1 = __builtin_amdgcn_mfma_f32_16x16x32_bf16(av, bv1, acc1, 0, 0, 0);
        acc2 = __builtin_amdgcn_mfma_f32_16x16x32_bf16(av, bv2, acc2, 0, 0, 0);
        acc3 = __builtin_amdgcn_mfma_f32_16x16x32_bf16(av, bv3, acc3, 0, 0, 0);
    }

    int rowD = mBase + quad * 4;
    #pragma unroll
    for (int nt = 0; nt < 4; ++nt) {
        int col = nBase + nt * 16 + l16;
        float bsum = 0.f;
        if (bias1) bsum += bias1[col];
        if (bias2) bsum += bias2[col];
        f32x4 a = (nt == 0) ? acc0 : (nt == 1) ? acc1 : (nt == 2) ? acc2 : acc3;
        #pragma unroll
        for (int r = 0; r < 4; ++r) {
            float v = a[r] + bsum;
            if (relu) v = v > 0.f ? v : 0.f;
            C[(size_t)(rowD + r) * N + col] = f2bf(v);
        }
    }
}

// ---------------------------------------------------------------------------
// delta features + batch reorder:
// feat[bs,t,0:256]=h[order[bs],t], [256:512]=d1, [512:768]=d2 (bf16)
// d1_at(s) computed from h at clamped absolute indices; d2 uses clamped
// d1-array positions (clamp OUTER index first, then inner h clamps).
// ---------------------------------------------------------------------------
__global__ void k_deltas(const unsigned short* __restrict__ hbuf, const int* __restrict__ order,
                         unsigned short* __restrict__ feat)
{
    int bt = blockIdx.x;        // bs*1024 + t
    int c  = threadIdx.x;       // 0..255
    int bs = bt >> 10, t = bt & 1023;
    int b  = order[bs];
    const unsigned short* hb = hbuf + (size_t)b * T_SZ * H3 + c;

    float hv[9];
    #pragma unroll
    for (int d = -4; d <= 4; ++d) {
        int tt = t + d;
        tt = tt < 0 ? 0 : (tt > T_SZ - 1 ? T_SZ - 1 : tt);
        hv[d + 4] = bf2f(hb[(size_t)tt * H3]);
    }
    float d1v[5];   // d1_at(s) for s=-2..2
    #pragma unroll
    for (int s = -2; s <= 2; ++s) {
        d1v[s + 2] = (hv[s + 5] - hv[s + 3]) * 0.5f + (hv[s + 6] - hv[s + 2]) * 0.25f;
    }
    int sp1 = (t + 1 > T_SZ - 1 ? T_SZ - 1 : t + 1) - t;
    int sm1 = (t - 1 < 0 ? 0 : t - 1) - t;
    int sp2 = (t + 2 > T_SZ - 1 ? T_SZ - 1 : t + 2) - t;
    int sm2 = (t - 2 < 0 ? 0 : t - 2) - t;
    float d2 = (d1v[2 + sp1] - d1v[2 + sm1]) * 0.5f + (d1v[2 + sp2] - d1v[2 + sm2]) * 0.25f;

    size_t fb = (size_t)bt * FEAT;
    feat[fb + c]       = hb[(size_t)t * H3];   // exact bf16 bits of h
    feat[fb + 256 + c] = f2bf(d1v[2]);
    feat[fb + 512 + c] = f2bf(d2);
}

// ---------------------------------------------------------------------------
// LSTM recurrence: one block per (sorted batch, direction). 512 threads,
// thread handles gate columns (2*tid, 2*tid+1). Whh pre-transposed to
// [K=256, N=1024] fp32 so weight loads are lane-contiguous (coalesced).
// Runs only len steps (padded outputs are masked to 0 anyway), writes
// backward outputs un-reversed, zeros the padded tail.
// ---------------------------------------------------------------------------
__global__ __launch_bounds__(512) void k_lstm(
    const unsigned short* __restrict__ gates_f, const unsigned short* __restrict__ gates_b,
    const float* __restrict__ wt_f, const float* __restrict__ wt_b,
    const float* __restrict__ h0, const float* __restrict__ c0,
    const int* __restrict__ lens_sorted, float* __restrict__ out)
{
    int bs = blockIdx.x, dir = blockIdx.y;
    int tid = threadIdx.x;
    const unsigned short* gates = (dir ? gates_b : gates_f) + (size_t)bs * T_SZ * G4;
    const float* Wt = dir ? wt_b : wt_f;

    __shared__ __align__(16) float h_lds[HH];
    __shared__ float g_lds[G4];

    float c_reg = 0.f;
    if (tid < HH) {
        h_lds[tid] = h0[(size_t)dir * B_SZ * HH + bs * HH + tid];
        c_reg      = c0[(size_t)dir * B_SZ * HH + bs * HH + tid];
    }
    __syncthreads();

    int len = lens_sorted[bs];
    int n0 = tid * 2;
    for (int t = 0; t < len; ++t) {
        unsigned int gpair = *(const unsigned int*)(const void*)(gates + (size_t)t * G4 + n0);
        float acc0 = bf2f((unsigned short)(gpair & 0xffffu));
        float acc1 = bf2f((unsigned short)(gpair >> 16));
        #pragma unroll
        for (int k8 = 0; k8 < HH; k8 += 8) {
            f32x4 h_a = *(const f32x4*)(const void*)&h_lds[k8];
            f32x4 h_b = *(const f32x4*)(const void*)&h_lds[k8 + 4];
            #pragma unroll
            for (int j = 0; j < 8; ++j) {
                float hk = (j < 4) ? h_a[j] : h_b[j - 4];
                const float* wp = Wt + (size_t)(k8 + j) * G4 + n0;
                float2 w = *(const float2*)(const void*)wp;
                acc0 = fmaf(w.x, hk, acc0);
                acc1 = fmaf(w.y, hk, acc1);
            }
        }
        g_lds[n0]     = acc0;
        g_lds[n0 + 1] = acc1;
        __syncthreads();
        if (tid < HH) {
            float gi = g_lds[tid];
            float gf = g_lds[HH + tid];
            float gg = g_lds[2 * HH + tid];
            float go = g_lds[3 * HH + tid];
            float si = 1.f / (1.f + __expf(-gi));
            float sf = 1.f / (1.f + __expf(-gf));
            float tg = 2.f / (1.f + __expf(-2.f * gg)) - 1.f;
            float so = 1.f / (1.f + __expf(-go));
            c_reg = sf * c_reg + si * tg;
            float tc = 2.f / (1.f + __expf(-2.f * c_reg)) - 1.f;
            float h = so * tc;
            h_lds[tid] = h;
            int t_out = dir ? (len - 1 - t) : t;
            out[((size_t)bs * T_SZ + t_out) * 512 + dir * HH + tid] = h;
        }
        __syncthreads();
    }
    // zero the masked/padded tail (d_out is poisoned before every launch)
    int total = (T_SZ - len) * HH;
    for (int idx = tid; idx < total; idx += 512) {
        int t = len + (idx >> 8);
        int j = idx & 255;
        out[((size_t)bs * T_SZ + t) * 512 + dir * HH + j] = 0.f;
    }
}

// ---------------------------------------------------------------------------
// Workspace layout (bytes, 256-aligned). gates_f overlaps dead a0/a1.
// Total ~203 MB.
// ---------------------------------------------------------------------------
#define OFF_XBF    ((size_t)0)
#define OFF_A0     ((size_t)5242880)
#define OFF_A1     ((size_t)38797312)
#define OFF_HBUF   ((size_t)72351744)
#define OFF_FEAT   ((size_t)89128960)
#define OFF_GF     OFF_A0                  /* 67,108,864 B over a0+a1 (dead) */
#define OFF_GB     ((size_t)139460608)
#define OFF_W0     ((size_t)206569472)
#define OFF_W1     ((size_t)206651392)
#define OFF_W2     ((size_t)207175680)
#define OFF_WIHF   ((size_t)207437824)
#define OFF_WIHB   ((size_t)209010688)
#define OFF_WTF    ((size_t)210583552)
#define OFF_WTB    ((size_t)211632128)
#define OFF_ORDER  ((size_t)212680704)
#define OFF_LENS   ((size_t)212680832)
#define OFF_ROWMAP ((size_t)212680960)

extern "C" void kernel_launch(void* const* d_in, const int* in_sizes, int n_in,
                              void* d_out, int out_size, void* d_ws, size_t ws_size,
                              hipStream_t stream)
{
    const float* x    = (const float*)d_in[0];
    const int*   xlen = (const int*)d_in[1];
    const float* eW0  = (const float*)d_in[2];
    const float* eb0  = (const float*)d_in[3];
    const float* eW1  = (const float*)d_in[4];
    const float* eb1  = (const float*)d_in[5];
    const float* eW2  = (const float*)d_in[6];
    const float* eb2  = (const float*)d_in[7];
    const float* Wihf = (const float*)d_in[8];
    const float* Whhf = (const float*)d_in[9];
    const float* bihf = (const float*)d_in[10];
    const float* bhhf = (const float*)d_in[11];
    const float* Wihb = (const float*)d_in[12];
    const float* Whhb = (const float*)d_in[13];
    const float* bihb = (const float*)d_in[14];
    const float* bhhb = (const float*)d_in[15];
    const float* h0   = (const float*)d_in[16];
    const float* c0   = (const float*)d_in[17];
    float* out = (float*)d_out;

    char* ws = (char*)d_ws;
    unsigned short* xbf    = (unsigned short*)(ws + OFF_XBF);
    unsigned short* a0     = (unsigned short*)(ws + OFF_A0);
    unsigned short* a1     = (unsigned short*)(ws + OFF_A1);
    unsigned short* hbuf   = (unsigned short*)(ws + OFF_HBUF);
    unsigned short* feat   = (unsigned short*)(ws + OFF_FEAT);
    unsigned short* gatesF = (unsigned short*)(ws + OFF_GF);
    unsigned short* gatesB = (unsigned short*)(ws + OFF_GB);
    unsigned short* w0     = (unsigned short*)(ws + OFF_W0);
    unsigned short* w1     = (unsigned short*)(ws + OFF_W1);
    unsigned short* w2     = (unsigned short*)(ws + OFF_W2);
    unsigned short* wihf   = (unsigned short*)(ws + OFF_WIHF);
    unsigned short* wihb   = (unsigned short*)(ws + OFF_WIHB);
    float* wtf             = (float*)(ws + OFF_WTF);
    float* wtb             = (float*)(ws + OFF_WTB);
    int* order             = (int*)(ws + OFF_ORDER);
    int* lens_sorted       = (int*)(ws + OFF_LENS);
    int* rowmap            = (int*)(ws + OFF_ROWMAP);

    // one-time prep (re-done every call; harness re-poisons ws)
    k_cvt<<<2048, 256, 0, stream>>>(x,    xbf,  B_SZ * T_SZ * DIN);
    k_cvt<<<160,  256, 0, stream>>>(eW0,  w0,   512 * 80);
    k_cvt<<<1024, 256, 0, stream>>>(eW1,  w1,   512 * 512);
    k_cvt<<<512,  256, 0, stream>>>(eW2,  w2,   256 * 512);
    k_cvt<<<2048, 256, 0, stream>>>(Wihf, wihf, 1024 * 768);
    k_cvt<<<2048, 256, 0, stream>>>(Wihb, wihb, 1024 * 768);
    k_transpose<<<1024, 256, 0, stream>>>(Whhf, wtf);
    k_transpose<<<1024, 256, 0, stream>>>(Whhb, wtb);
    k_order<<<1, 64, 0, stream>>>(xlen, order, lens_sorted, out + (size_t)B_SZ * T_SZ * 512);
    k_rowmap<<<128, 256, 0, stream>>>(lens_sorted, rowmap);

    // encoder: 80 -> 512 -> 512 -> 256, ReLU each layer
    k_gemm<<<dim3(1024, 4), 256, 0, stream>>>(xbf, w0, nullptr, eb0, nullptr, a0,   32768, 512, 80,  1);
    k_gemm<<<dim3(1024, 4), 256, 0, stream>>>(a0,  w1, nullptr, eb1, nullptr, a1,   32768, 512, 512, 1);
    k_gemm<<<dim3(1024, 2), 256, 0, stream>>>(a1,  w2, nullptr, eb2, nullptr, hbuf, 32768, 256, 512, 1);

    // delta features + sort reorder -> feat[bs,t,768]
    k_deltas<<<32768, 256, 0, stream>>>(hbuf, order, feat);

    // precompute gate inputs: feat @ Wih^T + (b_ih + b_hh), both directions
    k_gemm<<<dim3(1024, 8), 256, 0, stream>>>(feat, wihf, nullptr, bihf, bhhf, gatesF, 32768, 1024, 768, 0);
    k_gemm<<<dim3(1024, 8), 256, 0, stream>>>(feat, wihb, rowmap,  bihb, bhhb, gatesB, 32768, 1024, 768, 0);

    // serial recurrence: 64 independent chains (batch x dir)
    k_lstm<<<dim3(B_SZ, 2), 512, 0, stream>>>(gatesF, gatesB, wtf, wtb, h0, c0, lens_sorted, out);
}

// Round 2
// 9147.799 us; speedup vs baseline: 2.9947x; 2.9947x over previous
//
#include <hip/hip_runtime.h>
#include <cstdint>
#include <cstddef>

// ---------------------------------------------------------------------------
// Problem constants
// ---------------------------------------------------------------------------
#define B_SZ 32
#define T_SZ 1024
#define DIN  80
#define H3   256   // encoder output dim
#define FEAT 768   // 3 * H3
#define G4   1024  // 4 * H (LSTM gates)
#define HH   256   // LSTM hidden

typedef __attribute__((ext_vector_type(8))) short short8;   // 8 x bf16 (4 VGPRs)
typedef __attribute__((ext_vector_type(4))) float f32x4;    // MFMA accumulator

__device__ inline float bf2f(unsigned short u) {
    return __uint_as_float(((unsigned int)u) << 16);
}
__device__ inline unsigned short f2bf(float f) {
    unsigned int u = __float_as_uint(f);
    u += 0x7fffu + ((u >> 16) & 1u);   // RNE
    return (unsigned short)(u >> 16);
}
__device__ inline float sigm(float x) { return 1.f / (1.f + __expf(-x)); }
__device__ inline float tanh_f(float x) { return 2.f / (1.f + __expf(-2.f * x)) - 1.f; }

// ---------------------------------------------------------------------------
// fp32 -> bf16 conversion (grid-stride)
// ---------------------------------------------------------------------------
__global__ void k_cvt(const float* __restrict__ src, unsigned short* __restrict__ dst, int n) {
    int i = blockIdx.x * blockDim.x + threadIdx.x;
    int stride = gridDim.x * blockDim.x;
    for (; i < n; i += stride) dst[i] = f2bf(src[i]);
}

// ---------------------------------------------------------------------------
// stable argsort by descending length (matches jnp.argsort(-lens), stable)
// ---------------------------------------------------------------------------
__global__ void k_order(const int* __restrict__ lens, int* __restrict__ order,
                        int* __restrict__ lens_sorted, float* __restrict__ out_order) {
    int b = threadIdx.x;
    if (b < B_SZ) {
        int lb = lens[b];
        int r = 0;
        for (int j = 0; j < B_SZ; ++j) {
            int lj = lens[j];
            if (lj > lb || (lj == lb && j < b)) ++r;
        }
        order[r] = b;
        lens_sorted[r] = lb;
        out_order[r] = (float)b;   // second tuple output, as float
    }
}

// rowmap for backward direction: rowmap[bs*1024+t] = bs*1024 + clip(len-1-t, 0, 1023)
__global__ void k_rowmap(const int* __restrict__ lens_sorted, int* __restrict__ rowmap) {
    int idx = blockIdx.x * 256 + threadIdx.x;   // 32768 total
    int bs = idx >> 10, t = idx & 1023;
    int len = lens_sorted[bs];
    int src = len - 1 - t;
    src = src < 0 ? 0 : src;
    rowmap[idx] = (bs << 10) + src;
}

// stage h0 (fp32 [2,B,H]) into bf16 double-buffer slot 1 (read slot for s=0)
__global__ void k_h0(const float* __restrict__ h0, unsigned short* __restrict__ hbuf) {
    int i = blockIdx.x * 256 + threadIdx.x;   // 16384 total
    int dir = i >> 13, rc = i & 8191;         // rc = row*256+col
    hbuf[((size_t)(dir * 2 + 1) * B_SZ * HH) + rc] = f2bf(h0[(size_t)dir * B_SZ * HH + rc]);
}

// ---------------------------------------------------------------------------
// bf16 MFMA GEMM: C[M,N] = act(A[M,K] @ Bw[N,K]^T + bias1 + bias2), bf16 out.
// Block tile 32(M) x 128(N), 4 waves (2x2), each wave 16x64 via 4 accums.
// Fragment mapping per guide (m89/m91 verified).
// ---------------------------------------------------------------------------
__global__ __launch_bounds__(256) void k_gemm(
    const unsigned short* __restrict__ A, const unsigned short* __restrict__ Bw,
    const int* __restrict__ rowmap,
    const float* __restrict__ bias1, const float* __restrict__ bias2,
    unsigned short* __restrict__ C, int M, int N, int K, int relu)
{
    int tid  = threadIdx.x;
    int lane = tid & 63;
    int wave = tid >> 6;
    int waveM = wave >> 1, waveN = wave & 1;
    int l16  = lane & 15;
    int quad = lane >> 4;
    int mBase = blockIdx.x * 32 + waveM * 16;
    int nBase = blockIdx.y * 128 + waveN * 64;

    int mA = mBase + l16;
    int rowA = rowmap ? rowmap[mA] : mA;
    const unsigned short* pA  = A  + (size_t)rowA * K + quad * 8;
    const unsigned short* pB0 = Bw + (size_t)(nBase +  0 + l16) * K + quad * 8;
    const unsigned short* pB1 = Bw + (size_t)(nBase + 16 + l16) * K + quad * 8;
    const unsigned short* pB2 = Bw + (size_t)(nBase + 32 + l16) * K + quad * 8;
    const unsigned short* pB3 = Bw + (size_t)(nBase + 48 + l16) * K + quad * 8;

    const short8 z8 = {0, 0, 0, 0, 0, 0, 0, 0};
    f32x4 acc0 = {0.f, 0.f, 0.f, 0.f};
    f32x4 acc1 = acc0, acc2 = acc0, acc3 = acc0;

    for (int k0 = 0; k0 < K; k0 += 32) {
        bool ok = (k0 + quad * 8) < K;   // K % 8 == 0 for all layers (80,512,768)
        short8 av  = ok ? *(const short8*)(const void*)(pA  + k0) : z8;
        short8 bv0 = ok ? *(const short8*)(const void*)(pB0 + k0) : z8;
        short8 bv1 = ok ? *(const short8*)(const void*)(pB1 + k0) : z8;
        short8 bv2 = ok ? *(const short8*)(const void*)(pB2 + k0) : z8;
        short8 bv3 = ok ? *(const short8*)(const void*)(pB3 + k0) : z8;
        acc0 = __builtin_amdgcn_mfma_f32_16x16x32_bf16(av, bv0, acc0, 0, 0, 0);
        acc1 = __builtin_amdgcn_mfma_f32_16x16x32_bf16(av, bv1, acc1, 0, 0, 0);
        acc2 = __builtin_amdgcn_mfma_f32_16x16x32_bf16(av, bv2, acc2, 0, 0, 0);
        acc3 = __builtin_amdgcn_mfma_f32_16x16x32_bf16(av, bv3, acc3, 0, 0, 0);
    }

    int rowD = mBase + quad * 4;
    #pragma unroll
    for (int nt = 0; nt < 4; ++nt) {
        int col = nBase + nt * 16 + l16;
        float bsum = 0.f;
        if (bias1) bsum += bias1[col];
        if (bias2) bsum += bias2[col];
        f32x4 a = (nt == 0) ? acc0 : (nt == 1) ? acc1 : (nt == 2) ? acc2 : acc3;
        #pragma unroll
        for (int r = 0; r < 4; ++r) {
            float v = a[r] + bsum;
            if (relu) v = v > 0.f ? v : 0.f;
            C[(size_t)(rowD + r) * N + col] = f2bf(v);
        }
    }
}

// ---------------------------------------------------------------------------
// delta features + batch reorder (unchanged from round 0)
// ---------------------------------------------------------------------------
__global__ void k_deltas(const unsigned short* __restrict__ hbuf, const int* __restrict__ order,
                         unsigned short* __restrict__ feat)
{
    int bt = blockIdx.x;        // bs*1024 + t
    int c  = threadIdx.x;       // 0..255
    int bs = bt >> 10, t = bt & 1023;
    int b  = order[bs];
    const unsigned short* hb = hbuf + (size_t)b * T_SZ * H3 + c;

    float hv[9];
    #pragma unroll
    for (int d = -4; d <= 4; ++d) {
        int tt = t + d;
        tt = tt < 0 ? 0 : (tt > T_SZ - 1 ? T_SZ - 1 : tt);
        hv[d + 4] = bf2f(hb[(size_t)tt * H3]);
    }
    float d1v[5];   // d1_at(s) for s=-2..2
    #pragma unroll
    for (int s = -2; s <= 2; ++s) {
        d1v[s + 2] = (hv[s + 5] - hv[s + 3]) * 0.5f + (hv[s + 6] - hv[s + 2]) * 0.25f;
    }
    int sp1 = (t + 1 > T_SZ - 1 ? T_SZ - 1 : t + 1) - t;
    int sm1 = (t - 1 < 0 ? 0 : t - 1) - t;
    int sp2 = (t + 2 > T_SZ - 1 ? T_SZ - 1 : t + 2) - t;
    int sm2 = (t - 2 < 0 ? 0 : t - 2) - t;
    float d2 = (d1v[2 + sp1] - d1v[2 + sm1]) * 0.5f + (d1v[2 + sp2] - d1v[2 + sm2]) * 0.25f;

    size_t fb = (size_t)bt * FEAT;
    feat[fb + c]       = hb[(size_t)t * H3];   // exact bf16 bits of h
    feat[fb + 256 + c] = f2bf(d1v[2]);
    feat[fb + 512 + c] = f2bf(d2);
}

// ---------------------------------------------------------------------------
// Batched MFMA LSTM recurrence. 8 blocks: (dir 0..1) x (slice w 0..3).
// Each WG owns 64 hidden units (all 4 gates): Whh slice [256 cols x 256 K]
// pre-swizzled to MFMA B-fragment layout in 128 KB LDS (conflict-free
// ds_read_b128). c-state lives in registers across all steps. h is
// exchanged through a global bf16 double buffer with a device-scope
// monotone arrival counter per direction (4 arrivals per step).
// 512 threads = 8 waves: wave = (ntile<<1)|mtile; each wave computes the
// 16 hidden cols of its ntile for all 4 gates (4 accumulators), rows
// mtile*16..+16.
// ---------------------------------------------------------------------------
__global__ __launch_bounds__(512) void k_lstm_mfma(
    const unsigned short* __restrict__ gates_f, const unsigned short* __restrict__ gates_b,
    const float* __restrict__ Whh_f, const float* __restrict__ Whh_b,
    const float* __restrict__ c0, const int* __restrict__ lens_sorted,
    unsigned short* __restrict__ hbuf, unsigned int* __restrict__ flags,
    float* __restrict__ out)
{
    int wg  = blockIdx.x;        // 0..7
    int dir = wg >> 2;
    int w   = wg & 3;            // hidden slice: units [64w, 64w+64)
    const unsigned short* gates = dir ? gates_b : gates_f;
    const float* Whh = dir ? Whh_b : Whh_f;   // [1024, 256] fp32 row-major
    unsigned int* cnt = flags + dir * 32;     // 128 B apart per dir
    unsigned short* hb = hbuf + (size_t)dir * 2 * B_SZ * HH;

    // B-fragment LDS: [(nt*4+gb)*8+ks][lane*8+j] bf16, 128 KB
    __shared__ __align__(16) unsigned short Bf[4 * 4 * 8 * 512];

    int tid = threadIdx.x;
    for (int idx = tid; idx < 65536; idx += 512) {
        int blk = idx >> 9;          // (nt*4+gb)*8 + ks
        int e   = idx & 511;         // lane*8 + j
        int ln  = e >> 3, j = e & 7;
        int ks = blk & 7, gbnt = blk >> 3;
        int gb = gbnt & 3, nt = gbnt >> 2;
        int n = gb * 256 + w * 64 + nt * 16 + (ln & 15);
        int k = ks * 32 + (ln >> 4) * 8 + j;
        Bf[idx] = f2bf(Whh[(size_t)n * 256 + k]);
    }
    __syncthreads();

    int wave = tid >> 6, lane = tid & 63;
    int mt = wave & 1, nt = wave >> 1;
    int l16 = lane & 15, quad = lane >> 4;
    int col = w * 64 + nt * 16 + l16;          // global hidden col 0..255

    float c_[4];
    int   len_[4];
    size_t gin_base[4];
    #pragma unroll
    for (int r = 0; r < 4; ++r) {
        int row = mt * 16 + quad * 4 + r;
        c_[r]   = c0[(size_t)dir * B_SZ * HH + row * HH + col];
        len_[r] = lens_sorted[row];
        gin_base[r] = (size_t)row * T_SZ * G4 + col;
    }

    for (int s = 0; s < T_SZ; ++s) {
        // prefetch input-gate contributions (no h dependency -> hides latency
        // behind the arrival spin)
        float gin[4][4];
        #pragma unroll
        for (int r = 0; r < 4; ++r) {
            size_t base = gin_base[r] + (size_t)s * G4;
            #pragma unroll
            for (int gb = 0; gb < 4; ++gb)
                gin[gb][r] = bf2f(gates[base + gb * 256]);
        }

        // wait for h(s-1): 4 arrivals per completed step
        unsigned int target = 4u * (unsigned)s;
        while (__hip_atomic_load(cnt, __ATOMIC_ACQUIRE, __HIP_MEMORY_SCOPE_AGENT) < target) {}

        // A-fragments: h(s-1) from buffer ((s-1)&1) == ((s+1)&1)
        const unsigned short* hrd =
            hb + ((size_t)(((s + 1) & 1) * B_SZ + mt * 16 + l16)) * HH + quad * 8;
        short8 a[8];
        #pragma unroll
        for (int ks = 0; ks < 8; ++ks)
            a[ks] = *(const short8*)(const void*)(hrd + ks * 32);

        f32x4 acc[4];
        #pragma unroll
        for (int gb = 0; gb < 4; ++gb) acc[gb] = (f32x4){0.f, 0.f, 0.f, 0.f};

        #pragma unroll
        for (int ks = 0; ks < 8; ++ks) {
            #pragma unroll
            for (int gb = 0; gb < 4; ++gb) {
                short8 bfr = *(const short8*)(const void*)
                    (&Bf[(size_t)(((nt * 4 + gb) * 8 + ks) * 512) + lane * 8]);
                acc[gb] = __builtin_amdgcn_mfma_f32_16x16x32_bf16(a[ks], bfr, acc[gb], 0, 0, 0);
            }
        }

        // epilogue: gate nonlinearities, c/h update, stores
        #pragma unroll
        for (int r = 0; r < 4; ++r) {
            int row = mt * 16 + quad * 4 + r;
            float gi = acc[0][r] + gin[0][r];
            float gf = acc[1][r] + gin[1][r];
            float gg = acc[2][r] + gin[2][r];
            float go = acc[3][r] + gin[3][r];
            c_[r] = sigm(gf) * c_[r] + sigm(gi) * tanh_f(gg);
            float h = sigm(go) * tanh_f(c_[r]);
            hb[((size_t)((s & 1) * B_SZ + row)) * HH + col] = f2bf(h);
            bool valid = s < len_[r];
            int t_out = valid ? (dir ? (len_[r] - 1 - s) : s) : s;
            out[((size_t)row * T_SZ + t_out) * 512 + dir * HH + col] = valid ? h : 0.f;
        }

        __threadfence();      // device-scope release of h stores
        __syncthreads();      // all threads' fences complete before arrival
        if (tid == 0)
            __hip_atomic_fetch_add(cnt, 1u, __ATOMIC_RELEASE, __HIP_MEMORY_SCOPE_AGENT);
    }
}

// ---------------------------------------------------------------------------
// Workspace layout (bytes). hstate/flags reuse the dead xbf region (xbf is
// only live through the first encoder GEMM; k_h0/memset run after all GEMMs).
// ---------------------------------------------------------------------------
#define OFF_XBF    ((size_t)0)
#define OFF_HSTATE ((size_t)0)             /* 65536 B: bf16 h double-buffer   */
#define OFF_FLAGS  ((size_t)65536)         /* 256 B: arrival counters         */
#define OFF_A0     ((size_t)5242880)
#define OFF_A1     ((size_t)38797312)
#define OFF_HBUF   ((size_t)72351744)
#define OFF_FEAT   ((size_t)89128960)
#define OFF_GF     OFF_A0                  /* 67,108,864 B over a0+a1 (dead) */
#define OFF_GB     ((size_t)139460608)
#define OFF_W0     ((size_t)206569472)
#define OFF_W1     ((size_t)206651392)
#define OFF_W2     ((size_t)207175680)
#define OFF_WIHF   ((size_t)207437824)
#define OFF_WIHB   ((size_t)209010688)
#define OFF_ORDER  ((size_t)212680704)
#define OFF_LENS   ((size_t)212680832)
#define OFF_ROWMAP ((size_t)212680960)

extern "C" void kernel_launch(void* const* d_in, const int* in_sizes, int n_in,
                              void* d_out, int out_size, void* d_ws, size_t ws_size,
                              hipStream_t stream)
{
    const float* x    = (const float*)d_in[0];
    const int*   xlen = (const int*)d_in[1];
    const float* eW0  = (const float*)d_in[2];
    const float* eb0  = (const float*)d_in[3];
    const float* eW1  = (const float*)d_in[4];
    const float* eb1  = (const float*)d_in[5];
    const float* eW2  = (const float*)d_in[6];
    const float* eb2  = (const float*)d_in[7];
    const float* Wihf = (const float*)d_in[8];
    const float* Whhf = (const float*)d_in[9];
    const float* bihf = (const float*)d_in[10];
    const float* bhhf = (const float*)d_in[11];
    const float* Wihb = (const float*)d_in[12];
    const float* Whhb = (const float*)d_in[13];
    const float* bihb = (const float*)d_in[14];
    const float* bhhb = (const float*)d_in[15];
    const float* h0   = (const float*)d_in[16];
    const float* c0   = (const float*)d_in[17];
    float* out = (float*)d_out;

    char* ws = (char*)d_ws;
    unsigned short* xbf    = (unsigned short*)(ws + OFF_XBF);
    unsigned short* hstate = (unsigned short*)(ws + OFF_HSTATE);
    unsigned int*   flags  = (unsigned int*)(ws + OFF_FLAGS);
    unsigned short* a0     = (unsigned short*)(ws + OFF_A0);
    unsigned short* a1     = (unsigned short*)(ws + OFF_A1);
    unsigned short* hbuf   = (unsigned short*)(ws + OFF_HBUF);
    unsigned short* feat   = (unsigned short*)(ws + OFF_FEAT);
    unsigned short* gatesF = (unsigned short*)(ws + OFF_GF);
    unsigned short* gatesB = (unsigned short*)(ws + OFF_GB);
    unsigned short* w0     = (unsigned short*)(ws + OFF_W0);
    unsigned short* w1     = (unsigned short*)(ws + OFF_W1);
    unsigned short* w2     = (unsigned short*)(ws + OFF_W2);
    unsigned short* wihf   = (unsigned short*)(ws + OFF_WIHF);
    unsigned short* wihb   = (unsigned short*)(ws + OFF_WIHB);
    int* order             = (int*)(ws + OFF_ORDER);
    int* lens_sorted       = (int*)(ws + OFF_LENS);
    int* rowmap            = (int*)(ws + OFF_ROWMAP);

    // prep
    k_cvt<<<2048, 256, 0, stream>>>(x,    xbf,  B_SZ * T_SZ * DIN);
    k_cvt<<<160,  256, 0, stream>>>(eW0,  w0,   512 * 80);
    k_cvt<<<1024, 256, 0, stream>>>(eW1,  w1,   512 * 512);
    k_cvt<<<512,  256, 0, stream>>>(eW2,  w2,   256 * 512);
    k_cvt<<<2048, 256, 0, stream>>>(Wihf, wihf, 1024 * 768);
    k_cvt<<<2048, 256, 0, stream>>>(Wihb, wihb, 1024 * 768);
    k_order<<<1, 64, 0, stream>>>(xlen, order, lens_sorted, out + (size_t)B_SZ * T_SZ * 512);
    k_rowmap<<<128, 256, 0, stream>>>(lens_sorted, rowmap);

    // encoder: 80 -> 512 -> 512 -> 256, ReLU each layer
    k_gemm<<<dim3(1024, 4), 256, 0, stream>>>(xbf, w0, nullptr, eb0, nullptr, a0,   32768, 512, 80,  1);
    k_gemm<<<dim3(1024, 4), 256, 0, stream>>>(a0,  w1, nullptr, eb1, nullptr, a1,   32768, 512, 512, 1);
    k_gemm<<<dim3(1024, 2), 256, 0, stream>>>(a1,  w2, nullptr, eb2, nullptr, hbuf, 32768, 256, 512, 1);

    // delta features + sort reorder -> feat[bs,t,768]
    k_deltas<<<32768, 256, 0, stream>>>(hbuf, order, feat);

    // precompute gate inputs: feat @ Wih^T + (b_ih + b_hh), both directions
    k_gemm<<<dim3(1024, 8), 256, 0, stream>>>(feat, wihf, nullptr, bihf, bhhf, gatesF, 32768, 1024, 768, 0);
    k_gemm<<<dim3(1024, 8), 256, 0, stream>>>(feat, wihb, rowmap,  bihb, bhhb, gatesB, 32768, 1024, 768, 0);

    // LSTM recurrence: xbf region is dead now -> reuse for h state + flags
    hipMemsetAsync(flags, 0, 256, stream);
    k_h0<<<64, 256, 0, stream>>>(h0, hstate);
    k_lstm_mfma<<<8, 512, 0, stream>>>(gatesF, gatesB, Whhf, Whhb, c0, lens_sorted,
                                       hstate, flags, out);
}

// Round 3
// 5467.709 us; speedup vs baseline: 5.0102x; 1.6731x over previous
//
#include <hip/hip_runtime.h>
#include <cstdint>
#include <cstddef>

// ---------------------------------------------------------------------------
// Problem constants
// ---------------------------------------------------------------------------
#define B_SZ 32
#define T_SZ 1024
#define DIN  80
#define H3   256   // encoder output dim
#define FEAT 768   // 3 * H3
#define G4   1024  // 4 * H (LSTM gates)
#define HH   256   // LSTM hidden

typedef __attribute__((ext_vector_type(8))) short short8;   // 8 x bf16 (4 VGPRs)
typedef __attribute__((ext_vector_type(4))) float f32x4;    // MFMA accumulator

__device__ inline float bf2f(unsigned short u) {
    return __uint_as_float(((unsigned int)u) << 16);
}
__device__ inline unsigned short f2bf(float f) {
    unsigned int u = __float_as_uint(f);
    u += 0x7fffu + ((u >> 16) & 1u);   // RNE
    return (unsigned short)(u >> 16);
}
__device__ inline float sigm(float x) { return 1.f / (1.f + __expf(-x)); }
__device__ inline float tanh_f(float x) { return 2.f / (1.f + __expf(-2.f * x)) - 1.f; }

// ---------------------------------------------------------------------------
// fp32 -> bf16 conversion (grid-stride)
// ---------------------------------------------------------------------------
__global__ void k_cvt(const float* __restrict__ src, unsigned short* __restrict__ dst, int n) {
    int i = blockIdx.x * blockDim.x + threadIdx.x;
    int stride = gridDim.x * blockDim.x;
    for (; i < n; i += stride) dst[i] = f2bf(src[i]);
}

// ---------------------------------------------------------------------------
// stable argsort by descending length (matches jnp.argsort(-lens), stable)
// ---------------------------------------------------------------------------
__global__ void k_order(const int* __restrict__ lens, int* __restrict__ order,
                        int* __restrict__ lens_sorted, float* __restrict__ out_order) {
    int b = threadIdx.x;
    if (b < B_SZ) {
        int lb = lens[b];
        int r = 0;
        for (int j = 0; j < B_SZ; ++j) {
            int lj = lens[j];
            if (lj > lb || (lj == lb && j < b)) ++r;
        }
        order[r] = b;
        lens_sorted[r] = lb;
        out_order[r] = (float)b;   // second tuple output, as float
    }
}

// rowmap for backward direction: rowmap[bs*1024+t] = bs*1024 + clip(len-1-t, 0, 1023)
__global__ void k_rowmap(const int* __restrict__ lens_sorted, int* __restrict__ rowmap) {
    int idx = blockIdx.x * 256 + threadIdx.x;   // 32768 total
    int bs = idx >> 10, t = idx & 1023;
    int len = lens_sorted[bs];
    int src = len - 1 - t;
    src = src < 0 ? 0 : src;
    rowmap[idx] = (bs << 10) + src;
}

// zero the padded tail: out[bs, t, 0:512] = 0 for t >= len[bs]
__global__ void k_ztail(const int* __restrict__ lens_sorted, float* __restrict__ out) {
    int t = blockIdx.x, bs = blockIdx.y;
    if (t < lens_sorted[bs]) return;
    float4* p = (float4*)(out + ((size_t)bs * T_SZ + t) * 512);
    p[threadIdx.x] = make_float4(0.f, 0.f, 0.f, 0.f);   // 128 threads x 16B
}

// ---------------------------------------------------------------------------
// Whh [1024 rows (n), 256 cols (k)] fp32 -> fp8 e4m3 in MFMA B-fragment order:
// dst slot index = (ntile*8 + ks)*64 + lane, 8 bytes per slot,
// element j: n = ntile*16 + (lane&15), k = ks*32 + (lane>>4)*8 + j.
// One thread per slot (32768 threads per direction).
// ---------------------------------------------------------------------------
__global__ void k_wfrag8(const float* __restrict__ Whh, unsigned char* __restrict__ dst) {
    int t = blockIdx.x * 256 + threadIdx.x;   // 0..32767
    int lane = t & 63, ks = (t >> 6) & 7, ntile = t >> 9;
    int n = ntile * 16 + (lane & 15);
    int kb = ks * 32 + (lane >> 4) * 8;
    const float* p = Whh + (size_t)n * 256 + kb;
    float4 f0 = *(const float4*)(const void*)p;
    float4 f1 = *(const float4*)(const void*)(p + 4);
    unsigned int lo = (__builtin_amdgcn_cvt_pk_fp8_f32(f0.x, f0.y, 0, false) & 0xffff)
                    | (__builtin_amdgcn_cvt_pk_fp8_f32(f0.z, f0.w, 0, false) << 16);
    unsigned int hi = (__builtin_amdgcn_cvt_pk_fp8_f32(f1.x, f1.y, 0, false) & 0xffff)
                    | (__builtin_amdgcn_cvt_pk_fp8_f32(f1.z, f1.w, 0, false) << 16);
    ((uint2*)dst)[t] = make_uint2(lo, hi);
}

// ---------------------------------------------------------------------------
// bf16 MFMA GEMM: C[M,N] = act(A[M,K] @ Bw[N,K]^T + bias1 + bias2), bf16 out.
// Block tile 32(M) x 128(N), 4 waves (2x2), each wave 16x64 via 4 accums.
// ---------------------------------------------------------------------------
__global__ __launch_bounds__(256) void k_gemm(
    const unsigned short* __restrict__ A, const unsigned short* __restrict__ Bw,
    const int* __restrict__ rowmap,
    const float* __restrict__ bias1, const float* __restrict__ bias2,
    unsigned short* __restrict__ C, int M, int N, int K, int relu)
{
    int tid  = threadIdx.x;
    int lane = tid & 63;
    int wave = tid >> 6;
    int waveM = wave >> 1, waveN = wave & 1;
    int l16  = lane & 15;
    int quad = lane >> 4;
    int mBase = blockIdx.x * 32 + waveM * 16;
    int nBase = blockIdx.y * 128 + waveN * 64;

    int mA = mBase + l16;
    int rowA = rowmap ? rowmap[mA] : mA;
    const unsigned short* pA  = A  + (size_t)rowA * K + quad * 8;
    const unsigned short* pB0 = Bw + (size_t)(nBase +  0 + l16) * K + quad * 8;
    const unsigned short* pB1 = Bw + (size_t)(nBase + 16 + l16) * K + quad * 8;
    const unsigned short* pB2 = Bw + (size_t)(nBase + 32 + l16) * K + quad * 8;
    const unsigned short* pB3 = Bw + (size_t)(nBase + 48 + l16) * K + quad * 8;

    const short8 z8 = {0, 0, 0, 0, 0, 0, 0, 0};
    f32x4 acc0 = {0.f, 0.f, 0.f, 0.f};
    f32x4 acc1 = acc0, acc2 = acc0, acc3 = acc0;

    for (int k0 = 0; k0 < K; k0 += 32) {
        bool ok = (k0 + quad * 8) < K;
        short8 av  = ok ? *(const short8*)(const void*)(pA  + k0) : z8;
        short8 bv0 = ok ? *(const short8*)(const void*)(pB0 + k0) : z8;
        short8 bv1 = ok ? *(const short8*)(const void*)(pB1 + k0) : z8;
        short8 bv2 = ok ? *(const short8*)(const void*)(pB2 + k0) : z8;
        short8 bv3 = ok ? *(const short8*)(const void*)(pB3 + k0) : z8;
        acc0 = __builtin_amdgcn_mfma_f32_16x16x32_bf16(av, bv0, acc0, 0, 0, 0);
        acc1 = __builtin_amdgcn_mfma_f32_16x16x32_bf16(av, bv1, acc1, 0, 0, 0);
        acc2 = __builtin_amdgcn_mfma_f32_16x16x32_bf16(av, bv2, acc2, 0, 0, 0);
        acc3 = __builtin_amdgcn_mfma_f32_16x16x32_bf16(av, bv3, acc3, 0, 0, 0);
    }

    int rowD = mBase + quad * 4;
    #pragma unroll
    for (int nt = 0; nt < 4; ++nt) {
        int col = nBase + nt * 16 + l16;
        float bsum = 0.f;
        if (bias1) bsum += bias1[col];
        if (bias2) bsum += bias2[col];
        f32x4 a = (nt == 0) ? acc0 : (nt == 1) ? acc1 : (nt == 2) ? acc2 : acc3;
        #pragma unroll
        for (int r = 0; r < 4; ++r) {
            float v = a[r] + bsum;
            if (relu) v = v > 0.f ? v : 0.f;
            C[(size_t)(rowD + r) * N + col] = f2bf(v);
        }
    }
}

// ---------------------------------------------------------------------------
// delta features + batch reorder (unchanged)
// ---------------------------------------------------------------------------
__global__ void k_deltas(const unsigned short* __restrict__ hbuf, const int* __restrict__ order,
                         unsigned short* __restrict__ feat)
{
    int bt = blockIdx.x;        // bs*1024 + t
    int c  = threadIdx.x;       // 0..255
    int bs = bt >> 10, t = bt & 1023;
    int b  = order[bs];
    const unsigned short* hb = hbuf + (size_t)b * T_SZ * H3 + c;

    float hv[9];
    #pragma unroll
    for (int d = -4; d <= 4; ++d) {
        int tt = t + d;
        tt = tt < 0 ? 0 : (tt > T_SZ - 1 ? T_SZ - 1 : tt);
        hv[d + 4] = bf2f(hb[(size_t)tt * H3]);
    }
    float d1v[5];
    #pragma unroll
    for (int s = -2; s <= 2; ++s) {
        d1v[s + 2] = (hv[s + 5] - hv[s + 3]) * 0.5f + (hv[s + 6] - hv[s + 2]) * 0.25f;
    }
    int sp1 = (t + 1 > T_SZ - 1 ? T_SZ - 1 : t + 1) - t;
    int sm1 = (t - 1 < 0 ? 0 : t - 1) - t;
    int sp2 = (t + 2 > T_SZ - 1 ? T_SZ - 1 : t + 2) - t;
    int sm2 = (t - 2 < 0 ? 0 : t - 2) - t;
    float d2 = (d1v[2 + sp1] - d1v[2 + sm1]) * 0.5f + (d1v[2 + sp2] - d1v[2 + sm2]) * 0.25f;

    size_t fb = (size_t)bt * FEAT;
    feat[fb + c]       = hb[(size_t)t * H3];
    feat[fb + 256 + c] = f2bf(d1v[2]);
    feat[fb + 512 + c] = f2bf(d2);
}

// ---------------------------------------------------------------------------
// fp8 MFMA LSTM recurrence, batch-split: grid (half 0..1, dir 0..1) = 4 blocks.
// Each block owns 16 batch rows and the FULL fp8 Whh: gate-blocks 0,1 in
// 128 KB LDS, gate-blocks 2,3 register-resident (64 VGPRs/lane). Zero
// inter-block communication; one LDS h double-buffer + 1 barrier per step.
// 512 threads = 8 waves; wave w owns unit-tiles u = 2w, 2w+1 across all 4
// gate-blocks (8 accumulators). c-state in registers.
// Fragment maps (16x16x32, 8 elem/lane): A[m=lane&15][k=32ks+8quad+j],
// B[n=lane&15][k=32ks+8quad+j], D[col=lane&15][row=4quad+r].
// ---------------------------------------------------------------------------
__global__ __launch_bounds__(512, 2) void k_lstm_fp8(
    const unsigned short* __restrict__ gates_f, const unsigned short* __restrict__ gates_b,
    const unsigned char* __restrict__ wfrag8,
    const float* __restrict__ h0, const float* __restrict__ c0,
    const int* __restrict__ lens_sorted, float* __restrict__ out)
{
    int half = blockIdx.x, dir = blockIdx.y;
    int rowbase = half * 16;
    const unsigned short* gates = dir ? gates_b : gates_f;
    const unsigned char* wsrc = wfrag8 + (size_t)dir * 262144;

    __shared__ __align__(16) unsigned char Bf[131072];   // ntiles 0..31 (gates i,f)
    __shared__ __align__(16) unsigned char hA[2][4096];  // h as A-frags, double buf

    int tid = threadIdx.x;
    int wave = tid >> 6, lane = tid & 63;
    int l16 = lane & 15, quad = lane >> 4;

    // stage LDS weight half (straight copy: global layout == LDS layout)
    {
        const float4* s4 = (const float4*)(const void*)wsrc;
        float4* d4 = (float4*)(void*)Bf;
        for (int i = tid; i < 8192; i += 512) d4[i] = s4[i];
    }
    // register weight half: ntiles 32..63 (gates g,o)
    long long regB[2][2][8];
    {
        const long long* wsL = (const long long*)(const void*)(wsrc + 131072);
        #pragma unroll
        for (int gp = 0; gp < 2; ++gp)
            #pragma unroll
            for (int uu = 0; uu < 2; ++uu)
                #pragma unroll
                for (int ks = 0; ks < 8; ++ks)
                    regB[gp][uu][ks] = wsL[((gp * 16 + 2 * wave + uu) * 8 + ks) * 64 + lane];
    }
    // init h(-1) from h0 into hA[0] (slot = tid, 8 contiguous k per slot)
    {
        int ks = tid >> 6, ln = tid & 63;
        int m = ln & 15, kb = ks * 32 + (ln >> 4) * 8;
        const float* p = h0 + (size_t)dir * B_SZ * HH + (size_t)(rowbase + m) * HH + kb;
        float4 f0 = *(const float4*)(const void*)p;
        float4 f1 = *(const float4*)(const void*)(p + 4);
        unsigned int lo = (__builtin_amdgcn_cvt_pk_fp8_f32(f0.x, f0.y, 0, false) & 0xffff)
                        | (__builtin_amdgcn_cvt_pk_fp8_f32(f0.z, f0.w, 0, false) << 16);
        unsigned int hi = (__builtin_amdgcn_cvt_pk_fp8_f32(f1.x, f1.y, 0, false) & 0xffff)
                        | (__builtin_amdgcn_cvt_pk_fp8_f32(f1.z, f1.w, 0, false) << 16);
        ((uint2*)(void*)hA[0])[tid] = make_uint2(lo, hi);
    }

    // c-state + lens
    float c_[2][4];
    int len_[4];
    #pragma unroll
    for (int r = 0; r < 4; ++r) {
        len_[r] = lens_sorted[rowbase + quad * 4 + r];
        #pragma unroll
        for (int uu = 0; uu < 2; ++uu) {
            int col = (2 * wave + uu) * 16 + l16;
            c_[uu][r] = c0[(size_t)dir * B_SZ * HH + (size_t)(rowbase + quad * 4 + r) * HH + col];
        }
    }
    int maxlen = lens_sorted[rowbase];   // rows sorted desc -> first is longest
    __syncthreads();

    const long long* BfL = (const long long*)(const void*)Bf;

    for (int s = 0; s < maxlen; ++s) {
        // gate-input prefetch (global, consumed in epilogue ~2.5k cyc later)
        float gin[2][4][4];
        #pragma unroll
        for (int r = 0; r < 4; ++r) {
            const unsigned short* grow =
                gates + (size_t)(rowbase + quad * 4 + r) * T_SZ * G4 + (size_t)s * G4 + l16;
            #pragma unroll
            for (int uu = 0; uu < 2; ++uu)
                #pragma unroll
                for (int gb = 0; gb < 4; ++gb)
                    gin[uu][gb][r] = bf2f(grow[gb * 256 + (2 * wave + uu) * 16]);
        }

        // A-fragments: h(s-1)
        const long long* Ap = (const long long*)(const void*)hA[s & 1];
        long long a_[8];
        #pragma unroll
        for (int ks = 0; ks < 8; ++ks) a_[ks] = Ap[ks * 64 + lane];

        f32x4 acc[2][4];
        #pragma unroll
        for (int uu = 0; uu < 2; ++uu)
            #pragma unroll
            for (int gb = 0; gb < 4; ++gb) acc[uu][gb] = (f32x4){0.f, 0.f, 0.f, 0.f};

        #pragma unroll
        for (int ks = 0; ks < 8; ++ks) {
            #pragma unroll
            for (int uu = 0; uu < 2; ++uu) {
                int u = 2 * wave + uu;
                acc[uu][0] = __builtin_amdgcn_mfma_f32_16x16x32_fp8_fp8(
                    a_[ks], BfL[((u) * 8 + ks) * 64 + lane], acc[uu][0], 0, 0, 0);
                acc[uu][1] = __builtin_amdgcn_mfma_f32_16x16x32_fp8_fp8(
                    a_[ks], BfL[((16 + u) * 8 + ks) * 64 + lane], acc[uu][1], 0, 0, 0);
                acc[uu][2] = __builtin_amdgcn_mfma_f32_16x16x32_fp8_fp8(
                    a_[ks], regB[0][uu][ks], acc[uu][2], 0, 0, 0);
                acc[uu][3] = __builtin_amdgcn_mfma_f32_16x16x32_fp8_fp8(
                    a_[ks], regB[1][uu][ks], acc[uu][3], 0, 0, 0);
            }
        }

        // epilogue: nonlinearities, c/h update, h -> fp8 A-frag scatter, out
        unsigned char* hw = hA[(s + 1) & 1];
        #pragma unroll
        for (int uu = 0; uu < 2; ++uu) {
            int col = (2 * wave + uu) * 16 + l16;
            int ksp = col >> 5, qp = (col >> 3) & 3, jp = col & 7;
            #pragma unroll
            for (int r = 0; r < 4; ++r) {
                float gi = acc[uu][0][r] + gin[uu][0][r];
                float gf = acc[uu][1][r] + gin[uu][1][r];
                float gg = acc[uu][2][r] + gin[uu][2][r];
                float go = acc[uu][3][r] + gin[uu][3][r];
                c_[uu][r] = sigm(gf) * c_[uu][r] + sigm(gi) * tanh_f(gg);
                float h = sigm(go) * tanh_f(c_[uu][r]);
                int m = quad * 4 + r;
                hw[(ksp * 64 + qp * 16 + m) * 8 + jp] =
                    (unsigned char)(__builtin_amdgcn_cvt_pk_fp8_f32(h, h, 0, false) & 0xff);
                if (s < len_[r]) {
                    int t_out = dir ? (len_[r] - 1 - s) : s;
                    out[((size_t)(rowbase + m) * T_SZ + t_out) * 512 + dir * HH + col] = h;
                }
            }
        }
        __syncthreads();
    }
}

// ---------------------------------------------------------------------------
// Workspace layout (bytes). gates_f overlaps dead a0/a1 regions.
// ---------------------------------------------------------------------------
#define OFF_XBF    ((size_t)0)
#define OFF_A0     ((size_t)5242880)
#define OFF_A1     ((size_t)38797312)
#define OFF_HBUF   ((size_t)72351744)
#define OFF_FEAT   ((size_t)89128960)
#define OFF_GF     OFF_A0                  /* 67,108,864 B over a0+a1 (dead) */
#define OFF_GB     ((size_t)139460608)
#define OFF_W0     ((size_t)206569472)
#define OFF_W1     ((size_t)206651392)
#define OFF_W2     ((size_t)207175680)
#define OFF_WIHF   ((size_t)207437824)
#define OFF_WIHB   ((size_t)209010688)
#define OFF_WFRAG  ((size_t)210583552)     /* 524288 B: fp8 Whh fragments f+b */
#define OFF_ORDER  ((size_t)212680704)
#define OFF_LENS   ((size_t)212680832)
#define OFF_ROWMAP ((size_t)212680960)

extern "C" void kernel_launch(void* const* d_in, const int* in_sizes, int n_in,
                              void* d_out, int out_size, void* d_ws, size_t ws_size,
                              hipStream_t stream)
{
    const float* x    = (const float*)d_in[0];
    const int*   xlen = (const int*)d_in[1];
    const float* eW0  = (const float*)d_in[2];
    const float* eb0  = (const float*)d_in[3];
    const float* eW1  = (const float*)d_in[4];
    const float* eb1  = (const float*)d_in[5];
    const float* eW2  = (const float*)d_in[6];
    const float* eb2  = (const float*)d_in[7];
    const float* Wihf = (const float*)d_in[8];
    const float* Whhf = (const float*)d_in[9];
    const float* bihf = (const float*)d_in[10];
    const float* bhhf = (const float*)d_in[11];
    const float* Wihb = (const float*)d_in[12];
    const float* Whhb = (const float*)d_in[13];
    const float* bihb = (const float*)d_in[14];
    const float* bhhb = (const float*)d_in[15];
    const float* h0   = (const float*)d_in[16];
    const float* c0   = (const float*)d_in[17];
    float* out = (float*)d_out;

    char* ws = (char*)d_ws;
    unsigned short* xbf    = (unsigned short*)(ws + OFF_XBF);
    unsigned short* a0     = (unsigned short*)(ws + OFF_A0);
    unsigned short* a1     = (unsigned short*)(ws + OFF_A1);
    unsigned short* hbuf   = (unsigned short*)(ws + OFF_HBUF);
    unsigned short* feat   = (unsigned short*)(ws + OFF_FEAT);
    unsigned short* gatesF = (unsigned short*)(ws + OFF_GF);
    unsigned short* gatesB = (unsigned short*)(ws + OFF_GB);
    unsigned short* w0     = (unsigned short*)(ws + OFF_W0);
    unsigned short* w1     = (unsigned short*)(ws + OFF_W1);
    unsigned short* w2     = (unsigned short*)(ws + OFF_W2);
    unsigned short* wihf   = (unsigned short*)(ws + OFF_WIHF);
    unsigned short* wihb   = (unsigned short*)(ws + OFF_WIHB);
    unsigned char*  wfrag8 = (unsigned char*)(ws + OFF_WFRAG);
    int* order             = (int*)(ws + OFF_ORDER);
    int* lens_sorted       = (int*)(ws + OFF_LENS);
    int* rowmap            = (int*)(ws + OFF_ROWMAP);

    // prep
    k_cvt<<<2048, 256, 0, stream>>>(x,    xbf,  B_SZ * T_SZ * DIN);
    k_cvt<<<160,  256, 0, stream>>>(eW0,  w0,   512 * 80);
    k_cvt<<<1024, 256, 0, stream>>>(eW1,  w1,   512 * 512);
    k_cvt<<<512,  256, 0, stream>>>(eW2,  w2,   256 * 512);
    k_cvt<<<2048, 256, 0, stream>>>(Wihf, wihf, 1024 * 768);
    k_cvt<<<2048, 256, 0, stream>>>(Wihb, wihb, 1024 * 768);
    k_wfrag8<<<128, 256, 0, stream>>>(Whhf, wfrag8);
    k_wfrag8<<<128, 256, 0, stream>>>(Whhb, wfrag8 + 262144);
    k_order<<<1, 64, 0, stream>>>(xlen, order, lens_sorted, out + (size_t)B_SZ * T_SZ * 512);
    k_rowmap<<<128, 256, 0, stream>>>(lens_sorted, rowmap);
    k_ztail<<<dim3(T_SZ, B_SZ), 128, 0, stream>>>(lens_sorted, out);

    // encoder: 80 -> 512 -> 512 -> 256, ReLU each layer
    k_gemm<<<dim3(1024, 4), 256, 0, stream>>>(xbf, w0, nullptr, eb0, nullptr, a0,   32768, 512, 80,  1);
    k_gemm<<<dim3(1024, 4), 256, 0, stream>>>(a0,  w1, nullptr, eb1, nullptr, a1,   32768, 512, 512, 1);
    k_gemm<<<dim3(1024, 2), 256, 0, stream>>>(a1,  w2, nullptr, eb2, nullptr, hbuf, 32768, 256, 512, 1);

    // delta features + sort reorder -> feat[bs,t,768]
    k_deltas<<<32768, 256, 0, stream>>>(hbuf, order, feat);

    // precompute gate inputs: feat @ Wih^T + (b_ih + b_hh), both directions
    k_gemm<<<dim3(1024, 8), 256, 0, stream>>>(feat, wihf, nullptr, bihf, bhhf, gatesF, 32768, 1024, 768, 0);
    k_gemm<<<dim3(1024, 8), 256, 0, stream>>>(feat, wihb, rowmap,  bihb, bhhb, gatesB, 32768, 1024, 768, 0);

    // fp8 recurrence: 4 independent blocks (2 dirs x 2 batch halves), no sync
    k_lstm_fp8<<<dim3(2, 2), 512, 0, stream>>>(gatesF, gatesB, wfrag8, h0, c0,
                                               lens_sorted, out);
}

// Round 4
// 2922.014 us; speedup vs baseline: 9.3752x; 1.8712x over previous
//
#include <hip/hip_runtime.h>
#include <cstdint>
#include <cstddef>

// ---------------------------------------------------------------------------
// Problem constants
// ---------------------------------------------------------------------------
#define B_SZ 32
#define T_SZ 1024
#define DIN  80
#define H3   256   // encoder output dim
#define FEAT 768   // 3 * H3
#define G4   1024  // 4 * H (LSTM gates)
#define HH   256   // LSTM hidden

typedef __attribute__((ext_vector_type(8))) short short8;   // 8 x bf16 (4 VGPRs)
typedef __attribute__((ext_vector_type(4))) float f32x4;    // MFMA accumulator

__device__ inline float bf2f(unsigned short u) {
    return __uint_as_float(((unsigned int)u) << 16);
}
__device__ inline unsigned short f2bf(float f) {
    unsigned int u = __float_as_uint(f);
    u += 0x7fffu + ((u >> 16) & 1u);   // RNE
    return (unsigned short)(u >> 16);
}
// fast sigmoid/tanh: v_exp (exp2) + v_rcp, 4-5 VALU ops each
#define LOG2E 1.4426950408889634f
__device__ inline float sigm(float x) {
    return __builtin_amdgcn_rcpf(1.f + __builtin_amdgcn_exp2f(x * -LOG2E));
}
__device__ inline float tanh_f(float x) {
    // tanh(x) = 2/(1+exp(-2x)) - 1
    return fmaf(2.f, __builtin_amdgcn_rcpf(1.f + __builtin_amdgcn_exp2f(x * (-2.f * LOG2E))), -1.f);
}

// ---------------------------------------------------------------------------
// fp32 -> bf16 conversion (grid-stride)
// ---------------------------------------------------------------------------
__global__ void k_cvt(const float* __restrict__ src, unsigned short* __restrict__ dst, int n) {
    int i = blockIdx.x * blockDim.x + threadIdx.x;
    int stride = gridDim.x * blockDim.x;
    for (; i < n; i += stride) dst[i] = f2bf(src[i]);
}

// ---------------------------------------------------------------------------
// stable argsort by descending length (matches jnp.argsort(-lens), stable)
// ---------------------------------------------------------------------------
__global__ void k_order(const int* __restrict__ lens, int* __restrict__ order,
                        int* __restrict__ lens_sorted, float* __restrict__ out_order) {
    int b = threadIdx.x;
    if (b < B_SZ) {
        int lb = lens[b];
        int r = 0;
        for (int j = 0; j < B_SZ; ++j) {
            int lj = lens[j];
            if (lj > lb || (lj == lb && j < b)) ++r;
        }
        order[r] = b;
        lens_sorted[r] = lb;
        out_order[r] = (float)b;   // second tuple output, as float
    }
}

// rowmap for backward direction: rowmap[bs*1024+t] = bs*1024 + clip(len-1-t, 0, 1023)
__global__ void k_rowmap(const int* __restrict__ lens_sorted, int* __restrict__ rowmap) {
    int idx = blockIdx.x * 256 + threadIdx.x;   // 32768 total
    int bs = idx >> 10, t = idx & 1023;
    int len = lens_sorted[bs];
    int src = len - 1 - t;
    src = src < 0 ? 0 : src;
    rowmap[idx] = (bs << 10) + src;
}

// zero the padded tail: out[bs, t, 0:512] = 0 for t >= len[bs]
__global__ void k_ztail(const int* __restrict__ lens_sorted, float* __restrict__ out) {
    int t = blockIdx.x, bs = blockIdx.y;
    if (t < lens_sorted[bs]) return;
    float4* p = (float4*)(out + ((size_t)bs * T_SZ + t) * 512);
    p[threadIdx.x] = make_float4(0.f, 0.f, 0.f, 0.f);   // 128 threads x 16B
}

// ---------------------------------------------------------------------------
// Whh [1024 rows (n), 256 cols (k)] fp32 -> fp8 e4m3 in MFMA B-fragment order:
// dst slot index = (ntile*8 + ks)*64 + lane, 8 bytes per slot,
// element j: n = ntile*16 + (lane&15), k = ks*32 + (lane>>4)*8 + j.
// ---------------------------------------------------------------------------
__global__ void k_wfrag8(const float* __restrict__ Whh, unsigned char* __restrict__ dst) {
    int t = blockIdx.x * 256 + threadIdx.x;   // 0..32767
    int lane = t & 63, ks = (t >> 6) & 7, ntile = t >> 9;
    int n = ntile * 16 + (lane & 15);
    int kb = ks * 32 + (lane >> 4) * 8;
    const float* p = Whh + (size_t)n * 256 + kb;
    float4 f0 = *(const float4*)(const void*)p;
    float4 f1 = *(const float4*)(const void*)(p + 4);
    unsigned int lo = (__builtin_amdgcn_cvt_pk_fp8_f32(f0.x, f0.y, 0, false) & 0xffff)
                    | (__builtin_amdgcn_cvt_pk_fp8_f32(f0.z, f0.w, 0, false) << 16);
    unsigned int hi = (__builtin_amdgcn_cvt_pk_fp8_f32(f1.x, f1.y, 0, false) & 0xffff)
                    | (__builtin_amdgcn_cvt_pk_fp8_f32(f1.z, f1.w, 0, false) << 16);
    ((uint2*)dst)[t] = make_uint2(lo, hi);
}

// ---------------------------------------------------------------------------
// bf16 MFMA GEMM: C[M,N] = act(A[M,K] @ Bw[N,K]^T + bias1 + bias2), bf16 out.
// Block tile 32(M) x 128(N), 4 waves (2x2), each wave 16x64 via 4 accums.
// ---------------------------------------------------------------------------
__global__ __launch_bounds__(256) void k_gemm(
    const unsigned short* __restrict__ A, const unsigned short* __restrict__ Bw,
    const int* __restrict__ rowmap,
    const float* __restrict__ bias1, const float* __restrict__ bias2,
    unsigned short* __restrict__ C, int M, int N, int K, int relu)
{
    int tid  = threadIdx.x;
    int lane = tid & 63;
    int wave = tid >> 6;
    int waveM = wave >> 1, waveN = wave & 1;
    int l16  = lane & 15;
    int quad = lane >> 4;
    int mBase = blockIdx.x * 32 + waveM * 16;
    int nBase = blockIdx.y * 128 + waveN * 64;

    int mA = mBase + l16;
    int rowA = rowmap ? rowmap[mA] : mA;
    const unsigned short* pA  = A  + (size_t)rowA * K + quad * 8;
    const unsigned short* pB0 = Bw + (size_t)(nBase +  0 + l16) * K + quad * 8;
    const unsigned short* pB1 = Bw + (size_t)(nBase + 16 + l16) * K + quad * 8;
    const unsigned short* pB2 = Bw + (size_t)(nBase + 32 + l16) * K + quad * 8;
    const unsigned short* pB3 = Bw + (size_t)(nBase + 48 + l16) * K + quad * 8;

    const short8 z8 = {0, 0, 0, 0, 0, 0, 0, 0};
    f32x4 acc0 = {0.f, 0.f, 0.f, 0.f};
    f32x4 acc1 = acc0, acc2 = acc0, acc3 = acc0;

    for (int k0 = 0; k0 < K; k0 += 32) {
        bool ok = (k0 + quad * 8) < K;
        short8 av  = ok ? *(const short8*)(const void*)(pA  + k0) : z8;
        short8 bv0 = ok ? *(const short8*)(const void*)(pB0 + k0) : z8;
        short8 bv1 = ok ? *(const short8*)(const void*)(pB1 + k0) : z8;
        short8 bv2 = ok ? *(const short8*)(const void*)(pB2 + k0) : z8;
        short8 bv3 = ok ? *(const short8*)(const void*)(pB3 + k0) : z8;
        acc0 = __builtin_amdgcn_mfma_f32_16x16x32_bf16(av, bv0, acc0, 0, 0, 0);
        acc1 = __builtin_amdgcn_mfma_f32_16x16x32_bf16(av, bv1, acc1, 0, 0, 0);
        acc2 = __builtin_amdgcn_mfma_f32_16x16x32_bf16(av, bv2, acc2, 0, 0, 0);
        acc3 = __builtin_amdgcn_mfma_f32_16x16x32_bf16(av, bv3, acc3, 0, 0, 0);
    }

    int rowD = mBase + quad * 4;
    #pragma unroll
    for (int nt = 0; nt < 4; ++nt) {
        int col = nBase + nt * 16 + l16;
        float bsum = 0.f;
        if (bias1) bsum += bias1[col];
        if (bias2) bsum += bias2[col];
        f32x4 a = (nt == 0) ? acc0 : (nt == 1) ? acc1 : (nt == 2) ? acc2 : acc3;
        #pragma unroll
        for (int r = 0; r < 4; ++r) {
            float v = a[r] + bsum;
            if (relu) v = v > 0.f ? v : 0.f;
            C[(size_t)(rowD + r) * N + col] = f2bf(v);
        }
    }
}

// ---------------------------------------------------------------------------
// delta features + batch reorder (unchanged)
// ---------------------------------------------------------------------------
__global__ void k_deltas(const unsigned short* __restrict__ hbuf, const int* __restrict__ order,
                         unsigned short* __restrict__ feat)
{
    int bt = blockIdx.x;        // bs*1024 + t
    int c  = threadIdx.x;       // 0..255
    int bs = bt >> 10, t = bt & 1023;
    int b  = order[bs];
    const unsigned short* hb = hbuf + (size_t)b * T_SZ * H3 + c;

    float hv[9];
    #pragma unroll
    for (int d = -4; d <= 4; ++d) {
        int tt = t + d;
        tt = tt < 0 ? 0 : (tt > T_SZ - 1 ? T_SZ - 1 : tt);
        hv[d + 4] = bf2f(hb[(size_t)tt * H3]);
    }
    float d1v[5];
    #pragma unroll
    for (int s = -2; s <= 2; ++s) {
        d1v[s + 2] = (hv[s + 5] - hv[s + 3]) * 0.5f + (hv[s + 6] - hv[s + 2]) * 0.25f;
    }
    int sp1 = (t + 1 > T_SZ - 1 ? T_SZ - 1 : t + 1) - t;
    int sm1 = (t - 1 < 0 ? 0 : t - 1) - t;
    int sp2 = (t + 2 > T_SZ - 1 ? T_SZ - 1 : t + 2) - t;
    int sm2 = (t - 2 < 0 ? 0 : t - 2) - t;
    float d2 = (d1v[2 + sp1] - d1v[2 + sm1]) * 0.5f + (d1v[2 + sp2] - d1v[2 + sm2]) * 0.25f;

    size_t fb = (size_t)bt * FEAT;
    feat[fb + c]       = hb[(size_t)t * H3];
    feat[fb + 256 + c] = f2bf(d1v[2]);
    feat[fb + 512 + c] = f2bf(d2);
}

// ---------------------------------------------------------------------------
// fp8 MFMA LSTM recurrence v3: grid (rq 0..7, dir 0..1) = 16 blocks, each
// owning 4 batch rows + the FULL fp8 Whh register-resident (128 VGPRs/lane:
// regB[4 gates][2 utiles][8 ksteps]). Zero inter-block communication.
// Per step: MFMA phase (8 waves x 64 mfma, m-tile 16 with 4 valid rows) ->
// quad0 lanes write D (4 rows) to pad-5 LDS -> barrier -> ALL 512 threads do
// a uniform epilogue on 2 (row,col) elements each: coalesced dword gin loads,
// fast sigm/tanh (v_exp2+v_rcp), c in regs, h packed to fp8 A-frag LDS
// (ds_write_b16), float2 out store -> barrier.
// ---------------------------------------------------------------------------
__global__ __launch_bounds__(512, 2) void k_lstm_fp8(
    const unsigned short* __restrict__ gates_f, const unsigned short* __restrict__ gates_b,
    const unsigned char* __restrict__ wfrag8,
    const float* __restrict__ h0, const float* __restrict__ c0,
    const int* __restrict__ lens_sorted, float* __restrict__ out)
{
    int rq = blockIdx.x, dir = blockIdx.y;
    int rowbase = rq * 4;
    const unsigned short* gates = dir ? gates_b : gates_f;
    const unsigned char* wsrc = wfrag8 + (size_t)dir * 262144;

    __shared__ __align__(16) unsigned char hA[2][4096];  // h as A-frags (m-tile 16)
    __shared__ float g_lds[1024 * 5];                    // [gatecol][row], pad 5 (20 KB)

    int tid = threadIdx.x;
    int wave = tid >> 6, lane = tid & 63;
    int l16 = lane & 15, quad = lane >> 4;

    // full Whh register-resident: 64 x 8B = 128 VGPRs per lane
    long long regB[4][2][8];
    {
        const long long* wsL = (const long long*)(const void*)wsrc;
        #pragma unroll
        for (int gb = 0; gb < 4; ++gb)
            #pragma unroll
            for (int uu = 0; uu < 2; ++uu)
                #pragma unroll
                for (int ks = 0; ks < 8; ++ks)
                    regB[gb][uu][ks] = wsL[((size_t)((gb * 16 + 2 * wave + uu) * 8 + ks)) * 64 + lane];
    }

    // zero both hA buffers (rows 4..15 stay zero forever)
    for (int i = tid; i < 2048; i += 512) ((unsigned int*)(void*)hA)[i] = 0;
    __syncthreads();

    // epilogue ownership: thread -> (erow = tid>>7, cols ecol, ecol+1)
    int erow = tid >> 7;             // 0..3
    int ecol = (tid & 127) * 2;      // 0..254, even
    int grow_g = rowbase + erow;     // global sorted batch row

    // h0 -> hA[0] rows 0..3 (same mapping as per-step h writes)
    {
        float2 hv = *(const float2*)(const void*)
            (h0 + (size_t)dir * B_SZ * HH + (size_t)grow_g * HH + ecol);
        unsigned short pk = (unsigned short)
            (__builtin_amdgcn_cvt_pk_fp8_f32(hv.x, hv.y, 0, false) & 0xffff);
        int ks = ecol >> 5, q = (ecol >> 3) & 3, j = ecol & 7;
        *(unsigned short*)(void*)&hA[0][(ks * 64 + q * 16 + erow) * 8 + j] = pk;
    }

    float c2[2];
    c2[0] = c0[(size_t)dir * B_SZ * HH + (size_t)grow_g * HH + ecol];
    c2[1] = c0[(size_t)dir * B_SZ * HH + (size_t)grow_g * HH + ecol + 1];
    int elen = lens_sorted[grow_g];
    const unsigned short* gaddr = gates + (size_t)grow_g * T_SZ * G4 + ecol;
    float* outbase = out + (size_t)grow_g * T_SZ * 512 + dir * HH + ecol;

    int maxlen = lens_sorted[rowbase];   // rows sorted desc
    __syncthreads();

    for (int s = 0; s < maxlen; ++s) {
        // prefetch gin: 4 coalesced dword loads (2 bf16 each), consumed post-barrier
        unsigned int gpk[4];
        #pragma unroll
        for (int gb = 0; gb < 4; ++gb)
            gpk[gb] = *(const unsigned int*)(const void*)(gaddr + (size_t)s * G4 + gb * 256);

        // A-fragments: h(s-1)
        const long long* Ap = (const long long*)(const void*)hA[s & 1];
        long long a_[8];
        #pragma unroll
        for (int ks = 0; ks < 8; ++ks) a_[ks] = Ap[ks * 64 + lane];

        f32x4 acc[2][4];
        #pragma unroll
        for (int uu = 0; uu < 2; ++uu)
            #pragma unroll
            for (int gb = 0; gb < 4; ++gb) acc[uu][gb] = (f32x4){0.f, 0.f, 0.f, 0.f};

        #pragma unroll
        for (int ks = 0; ks < 8; ++ks)
            #pragma unroll
            for (int uu = 0; uu < 2; ++uu)
                #pragma unroll
                for (int gb = 0; gb < 4; ++gb)
                    acc[uu][gb] = __builtin_amdgcn_mfma_f32_16x16x32_fp8_fp8(
                        a_[ks], regB[gb][uu][ks], acc[uu][gb], 0, 0, 0);

        // quad0 lanes hold the 4 valid rows (D row = quad*4+r): write to LDS
        if (quad == 0) {
            #pragma unroll
            for (int uu = 0; uu < 2; ++uu)
                #pragma unroll
                for (int gb = 0; gb < 4; ++gb) {
                    int gc = gb * 256 + (2 * wave + uu) * 16 + l16;
                    #pragma unroll
                    for (int r = 0; r < 4; ++r)
                        g_lds[gc * 5 + r] = acc[uu][gb][r];
                }
        }
        __syncthreads();

        // uniform epilogue: 2 elements per thread
        float h2[2];
        #pragma unroll
        for (int i = 0; i < 2; ++i) {
            int col = ecol + i;
            float gi = g_lds[(0 * 256 + col) * 5 + erow]
                     + bf2f(i ? (unsigned short)(gpk[0] >> 16) : (unsigned short)(gpk[0] & 0xffff));
            float gf = g_lds[(1 * 256 + col) * 5 + erow]
                     + bf2f(i ? (unsigned short)(gpk[1] >> 16) : (unsigned short)(gpk[1] & 0xffff));
            float gg = g_lds[(2 * 256 + col) * 5 + erow]
                     + bf2f(i ? (unsigned short)(gpk[2] >> 16) : (unsigned short)(gpk[2] & 0xffff));
            float go = g_lds[(3 * 256 + col) * 5 + erow]
                     + bf2f(i ? (unsigned short)(gpk[3] >> 16) : (unsigned short)(gpk[3] & 0xffff));
            c2[i] = sigm(gf) * c2[i] + sigm(gi) * tanh_f(gg);
            h2[i] = sigm(go) * tanh_f(c2[i]);
        }
        // h -> fp8 A-frag (2 adjacent bytes = one b16 write)
        {
            unsigned short pk = (unsigned short)
                (__builtin_amdgcn_cvt_pk_fp8_f32(h2[0], h2[1], 0, false) & 0xffff);
            int ks = ecol >> 5, q = (ecol >> 3) & 3, j = ecol & 7;
            *(unsigned short*)(void*)&hA[(s + 1) & 1][(ks * 64 + q * 16 + erow) * 8 + j] = pk;
        }
        if (s < elen) {
            int t_out = dir ? (elen - 1 - s) : s;
            *(float2*)(void*)(outbase + (size_t)t_out * 512) = make_float2(h2[0], h2[1]);
        }
        __syncthreads();
    }
}

// ---------------------------------------------------------------------------
// Workspace layout (bytes). gates_f overlaps dead a0/a1 regions.
// ---------------------------------------------------------------------------
#define OFF_XBF    ((size_t)0)
#define OFF_A0     ((size_t)5242880)
#define OFF_A1     ((size_t)38797312)
#define OFF_HBUF   ((size_t)72351744)
#define OFF_FEAT   ((size_t)89128960)
#define OFF_GF     OFF_A0                  /* 67,108,864 B over a0+a1 (dead) */
#define OFF_GB     ((size_t)139460608)
#define OFF_W0     ((size_t)206569472)
#define OFF_W1     ((size_t)206651392)
#define OFF_W2     ((size_t)207175680)
#define OFF_WIHF   ((size_t)207437824)
#define OFF_WIHB   ((size_t)209010688)
#define OFF_WFRAG  ((size_t)210583552)     /* 524288 B: fp8 Whh fragments f+b */
#define OFF_ORDER  ((size_t)212680704)
#define OFF_LENS   ((size_t)212680832)
#define OFF_ROWMAP ((size_t)212680960)

extern "C" void kernel_launch(void* const* d_in, const int* in_sizes, int n_in,
                              void* d_out, int out_size, void* d_ws, size_t ws_size,
                              hipStream_t stream)
{
    const float* x    = (const float*)d_in[0];
    const int*   xlen = (const int*)d_in[1];
    const float* eW0  = (const float*)d_in[2];
    const float* eb0  = (const float*)d_in[3];
    const float* eW1  = (const float*)d_in[4];
    const float* eb1  = (const float*)d_in[5];
    const float* eW2  = (const float*)d_in[6];
    const float* eb2  = (const float*)d_in[7];
    const float* Wihf = (const float*)d_in[8];
    const float* Whhf = (const float*)d_in[9];
    const float* bihf = (const float*)d_in[10];
    const float* bhhf = (const float*)d_in[11];
    const float* Wihb = (const float*)d_in[12];
    const float* Whhb = (const float*)d_in[13];
    const float* bihb = (const float*)d_in[14];
    const float* bhhb = (const float*)d_in[15];
    const float* h0   = (const float*)d_in[16];
    const float* c0   = (const float*)d_in[17];
    float* out = (float*)d_out;

    char* ws = (char*)d_ws;
    unsigned short* xbf    = (unsigned short*)(ws + OFF_XBF);
    unsigned short* a0     = (unsigned short*)(ws + OFF_A0);
    unsigned short* a1     = (unsigned short*)(ws + OFF_A1);
    unsigned short* hbuf   = (unsigned short*)(ws + OFF_HBUF);
    unsigned short* feat   = (unsigned short*)(ws + OFF_FEAT);
    unsigned short* gatesF = (unsigned short*)(ws + OFF_GF);
    unsigned short* gatesB = (unsigned short*)(ws + OFF_GB);
    unsigned short* w0     = (unsigned short*)(ws + OFF_W0);
    unsigned short* w1     = (unsigned short*)(ws + OFF_W1);
    unsigned short* w2     = (unsigned short*)(ws + OFF_W2);
    unsigned short* wihf   = (unsigned short*)(ws + OFF_WIHF);
    unsigned short* wihb   = (unsigned short*)(ws + OFF_WIHB);
    unsigned char*  wfrag8 = (unsigned char*)(ws + OFF_WFRAG);
    int* order             = (int*)(ws + OFF_ORDER);
    int* lens_sorted       = (int*)(ws + OFF_LENS);
    int* rowmap            = (int*)(ws + OFF_ROWMAP);

    // prep
    k_cvt<<<2048, 256, 0, stream>>>(x,    xbf,  B_SZ * T_SZ * DIN);
    k_cvt<<<160,  256, 0, stream>>>(eW0,  w0,   512 * 80);
    k_cvt<<<1024, 256, 0, stream>>>(eW1,  w1,   512 * 512);
    k_cvt<<<512,  256, 0, stream>>>(eW2,  w2,   256 * 512);
    k_cvt<<<2048, 256, 0, stream>>>(Wihf, wihf, 1024 * 768);
    k_cvt<<<2048, 256, 0, stream>>>(Wihb, wihb, 1024 * 768);
    k_wfrag8<<<128, 256, 0, stream>>>(Whhf, wfrag8);
    k_wfrag8<<<128, 256, 0, stream>>>(Whhb, wfrag8 + 262144);
    k_order<<<1, 64, 0, stream>>>(xlen, order, lens_sorted, out + (size_t)B_SZ * T_SZ * 512);
    k_rowmap<<<128, 256, 0, stream>>>(lens_sorted, rowmap);
    k_ztail<<<dim3(T_SZ, B_SZ), 128, 0, stream>>>(lens_sorted, out);

    // encoder: 80 -> 512 -> 512 -> 256, ReLU each layer
    k_gemm<<<dim3(1024, 4), 256, 0, stream>>>(xbf, w0, nullptr, eb0, nullptr, a0,   32768, 512, 80,  1);
    k_gemm<<<dim3(1024, 4), 256, 0, stream>>>(a0,  w1, nullptr, eb1, nullptr, a1,   32768, 512, 512, 1);
    k_gemm<<<dim3(1024, 2), 256, 0, stream>>>(a1,  w2, nullptr, eb2, nullptr, hbuf, 32768, 256, 512, 1);

    // delta features + sort reorder -> feat[bs,t,768]
    k_deltas<<<32768, 256, 0, stream>>>(hbuf, order, feat);

    // precompute gate inputs: feat @ Wih^T + (b_ih + b_hh), both directions
    k_gemm<<<dim3(1024, 8), 256, 0, stream>>>(feat, wihf, nullptr, bihf, bhhf, gatesF, 32768, 1024, 768, 0);
    k_gemm<<<dim3(1024, 8), 256, 0, stream>>>(feat, wihb, rowmap,  bihb, bhhb, gatesB, 32768, 1024, 768, 0);

    // fp8 recurrence: 16 independent blocks (2 dirs x 8 batch quads), no sync
    k_lstm_fp8<<<dim3(8, 2), 512, 0, stream>>>(gatesF, gatesB, wfrag8, h0, c0,
                                               lens_sorted, out);
}

// Round 5
// 2747.588 us; speedup vs baseline: 9.9704x; 1.0635x over previous
//
#include <hip/hip_runtime.h>
#include <cstdint>
#include <cstddef>

// ---------------------------------------------------------------------------
// Problem constants
// ---------------------------------------------------------------------------
#define B_SZ 32
#define T_SZ 1024
#define DIN  80
#define H3   256   // encoder output dim
#define FEAT 768   // 3 * H3
#define G4   1024  // 4 * H (LSTM gates)
#define HH   256   // LSTM hidden

typedef __attribute__((ext_vector_type(8))) short short8;   // 8 x bf16 (4 VGPRs)
typedef __attribute__((ext_vector_type(4))) float f32x4;    // MFMA accumulator
typedef __attribute__((ext_vector_type(2))) long long llong2;

__device__ inline float bf2f(unsigned short u) {
    return __uint_as_float(((unsigned int)u) << 16);
}
__device__ inline unsigned short f2bf(float f) {
    unsigned int u = __float_as_uint(f);
    u += 0x7fffu + ((u >> 16) & 1u);   // RNE
    return (unsigned short)(u >> 16);
}
// fast sigmoid/tanh: v_exp (exp2) + v_rcp
#define LOG2E 1.4426950408889634f
__device__ inline float sigm(float x) {
    return __builtin_amdgcn_rcpf(1.f + __builtin_amdgcn_exp2f(x * -LOG2E));
}
__device__ inline float tanh_f(float x) {
    return fmaf(2.f, __builtin_amdgcn_rcpf(1.f + __builtin_amdgcn_exp2f(x * (-2.f * LOG2E))), -1.f);
}

// ---------------------------------------------------------------------------
// fp32 -> bf16 conversion (grid-stride)
// ---------------------------------------------------------------------------
__global__ void k_cvt(const float* __restrict__ src, unsigned short* __restrict__ dst, int n) {
    int i = blockIdx.x * blockDim.x + threadIdx.x;
    int stride = gridDim.x * blockDim.x;
    for (; i < n; i += stride) dst[i] = f2bf(src[i]);
}

// ---------------------------------------------------------------------------
// stable argsort by descending length (matches jnp.argsort(-lens), stable)
// ---------------------------------------------------------------------------
__global__ void k_order(const int* __restrict__ lens, int* __restrict__ order,
                        int* __restrict__ lens_sorted, float* __restrict__ out_order) {
    int b = threadIdx.x;
    if (b < B_SZ) {
        int lb = lens[b];
        int r = 0;
        for (int j = 0; j < B_SZ; ++j) {
            int lj = lens[j];
            if (lj > lb || (lj == lb && j < b)) ++r;
        }
        order[r] = b;
        lens_sorted[r] = lb;
        out_order[r] = (float)b;   // second tuple output, as float
    }
}

// rowmap for backward direction: rowmap[bs*1024+t] = bs*1024 + clip(len-1-t, 0, 1023)
__global__ void k_rowmap(const int* __restrict__ lens_sorted, int* __restrict__ rowmap) {
    int idx = blockIdx.x * 256 + threadIdx.x;   // 32768 total
    int bs = idx >> 10, t = idx & 1023;
    int len = lens_sorted[bs];
    int src = len - 1 - t;
    src = src < 0 ? 0 : src;
    rowmap[idx] = (bs << 10) + src;
}

// zero the padded tail: out[bs, t, 0:512] = 0 for t >= len[bs]
__global__ void k_ztail(const int* __restrict__ lens_sorted, float* __restrict__ out) {
    int t = blockIdx.x, bs = blockIdx.y;
    if (t < lens_sorted[bs]) return;
    float4* p = (float4*)(out + ((size_t)bs * T_SZ + t) * 512);
    p[threadIdx.x] = make_float4(0.f, 0.f, 0.f, 0.f);   // 128 threads x 16B
}

// ---------------------------------------------------------------------------
// Whh [1024 rows (n), 256 cols (k)] fp32 -> fp8 e4m3 in MFMA B-fragment order:
// dst slot index = (ntile*8 + ks)*64 + lane, 8 bytes per slot,
// element j: n = ntile*16 + (lane&15), k = ks*32 + (lane>>4)*8 + j.
// ---------------------------------------------------------------------------
__global__ void k_wfrag8(const float* __restrict__ Whh, unsigned char* __restrict__ dst) {
    int t = blockIdx.x * 256 + threadIdx.x;   // 0..32767
    int lane = t & 63, ks = (t >> 6) & 7, ntile = t >> 9;
    int n = ntile * 16 + (lane & 15);
    int kb = ks * 32 + (lane >> 4) * 8;
    const float* p = Whh + (size_t)n * 256 + kb;
    float4 f0 = *(const float4*)(const void*)p;
    float4 f1 = *(const float4*)(const void*)(p + 4);
    unsigned int lo = (__builtin_amdgcn_cvt_pk_fp8_f32(f0.x, f0.y, 0, false) & 0xffff)
                    | (__builtin_amdgcn_cvt_pk_fp8_f32(f0.z, f0.w, 0, false) << 16);
    unsigned int hi = (__builtin_amdgcn_cvt_pk_fp8_f32(f1.x, f1.y, 0, false) & 0xffff)
                    | (__builtin_amdgcn_cvt_pk_fp8_f32(f1.z, f1.w, 0, false) << 16);
    ((uint2*)dst)[t] = make_uint2(lo, hi);
}

// ---------------------------------------------------------------------------
// bf16 MFMA GEMM: C[M,N] = act(A[M,K] @ Bw[N,K]^T + bias1 + bias2), bf16 out.
// Block tile 32(M) x 128(N), 4 waves (2x2), each wave 16x64 via 4 accums.
// layout=0: row-major C[M,N].
// layout=1: LSTM gate layout (per rq buffer of 4 Mi bf16):
//   idx = rq*4194304 + ((t*8 + w)*64 + l16c*4 + b4)*8 + uu*4 + gb
//   where row=bs*1024+t, rq=bs>>2, b4=bs&3; col: gb=col>>8, cu=(col>>4)&15,
//   l16c=col&15, w=cu>>1, uu=cu&1. Gives the LSTM kernel one dwordx4 load
//   per lane per step (lane-packed 8 bf16 = [uu][gb]).
// ---------------------------------------------------------------------------
__global__ __launch_bounds__(256) void k_gemm(
    const unsigned short* __restrict__ A, const unsigned short* __restrict__ Bw,
    const int* __restrict__ rowmap,
    const float* __restrict__ bias1, const float* __restrict__ bias2,
    unsigned short* __restrict__ C, int M, int N, int K, int relu, int layout)
{
    int tid  = threadIdx.x;
    int lane = tid & 63;
    int wave = tid >> 6;
    int waveM = wave >> 1, waveN = wave & 1;
    int l16  = lane & 15;
    int quad = lane >> 4;
    int mBase = blockIdx.x * 32 + waveM * 16;
    int nBase = blockIdx.y * 128 + waveN * 64;

    int mA = mBase + l16;
    int rowA = rowmap ? rowmap[mA] : mA;
    const unsigned short* pA  = A  + (size_t)rowA * K + quad * 8;
    const unsigned short* pB0 = Bw + (size_t)(nBase +  0 + l16) * K + quad * 8;
    const unsigned short* pB1 = Bw + (size_t)(nBase + 16 + l16) * K + quad * 8;
    const unsigned short* pB2 = Bw + (size_t)(nBase + 32 + l16) * K + quad * 8;
    const unsigned short* pB3 = Bw + (size_t)(nBase + 48 + l16) * K + quad * 8;

    const short8 z8 = {0, 0, 0, 0, 0, 0, 0, 0};
    f32x4 acc0 = {0.f, 0.f, 0.f, 0.f};
    f32x4 acc1 = acc0, acc2 = acc0, acc3 = acc0;

    for (int k0 = 0; k0 < K; k0 += 32) {
        bool ok = (k0 + quad * 8) < K;
        short8 av  = ok ? *(const short8*)(const void*)(pA  + k0) : z8;
        short8 bv0 = ok ? *(const short8*)(const void*)(pB0 + k0) : z8;
        short8 bv1 = ok ? *(const short8*)(const void*)(pB1 + k0) : z8;
        short8 bv2 = ok ? *(const short8*)(const void*)(pB2 + k0) : z8;
        short8 bv3 = ok ? *(const short8*)(const void*)(pB3 + k0) : z8;
        acc0 = __builtin_amdgcn_mfma_f32_16x16x32_bf16(av, bv0, acc0, 0, 0, 0);
        acc1 = __builtin_amdgcn_mfma_f32_16x16x32_bf16(av, bv1, acc1, 0, 0, 0);
        acc2 = __builtin_amdgcn_mfma_f32_16x16x32_bf16(av, bv2, acc2, 0, 0, 0);
        acc3 = __builtin_amdgcn_mfma_f32_16x16x32_bf16(av, bv3, acc3, 0, 0, 0);
    }

    int rowD = mBase + quad * 4;
    #pragma unroll
    for (int nt = 0; nt < 4; ++nt) {
        int col = nBase + nt * 16 + l16;
        float bsum = 0.f;
        if (bias1) bsum += bias1[col];
        if (bias2) bsum += bias2[col];
        f32x4 a = (nt == 0) ? acc0 : (nt == 1) ? acc1 : (nt == 2) ? acc2 : acc3;
        #pragma unroll
        for (int r = 0; r < 4; ++r) {
            float v = a[r] + bsum;
            if (relu) v = v > 0.f ? v : 0.f;
            if (layout == 0) {
                C[(size_t)(rowD + r) * N + col] = f2bf(v);
            } else {
                int row = rowD + r;
                int bs = row >> 10, t = row & 1023;
                int rq = bs >> 2, b4 = bs & 3;
                int gb = col >> 8, cu = (col >> 4) & 15, l16c = col & 15;
                int w = cu >> 1, uu = cu & 1;
                size_t idx = (size_t)rq * 4194304
                           + ((size_t)(t * 8 + w) * 64 + l16c * 4 + b4) * 8 + uu * 4 + gb;
                C[idx] = f2bf(v);
            }
        }
    }
}

// ---------------------------------------------------------------------------
// delta features + batch reorder (unchanged)
// ---------------------------------------------------------------------------
__global__ void k_deltas(const unsigned short* __restrict__ hbuf, const int* __restrict__ order,
                         unsigned short* __restrict__ feat)
{
    int bt = blockIdx.x;        // bs*1024 + t
    int c  = threadIdx.x;       // 0..255
    int bs = bt >> 10, t = bt & 1023;
    int b  = order[bs];
    const unsigned short* hb = hbuf + (size_t)b * T_SZ * H3 + c;

    float hv[9];
    #pragma unroll
    for (int d = -4; d <= 4; ++d) {
        int tt = t + d;
        tt = tt < 0 ? 0 : (tt > T_SZ - 1 ? T_SZ - 1 : tt);
        hv[d + 4] = bf2f(hb[(size_t)tt * H3]);
    }
    float d1v[5];
    #pragma unroll
    for (int s = -2; s <= 2; ++s) {
        d1v[s + 2] = (hv[s + 5] - hv[s + 3]) * 0.5f + (hv[s + 6] - hv[s + 2]) * 0.25f;
    }
    int sp1 = (t + 1 > T_SZ - 1 ? T_SZ - 1 : t + 1) - t;
    int sm1 = (t - 1 < 0 ? 0 : t - 1) - t;
    int sp2 = (t + 2 > T_SZ - 1 ? T_SZ - 1 : t + 2) - t;
    int sm2 = (t - 2 < 0 ? 0 : t - 2) - t;
    float d2 = (d1v[2 + sp1] - d1v[2 + sm1]) * 0.5f + (d1v[2 + sp2] - d1v[2 + sm2]) * 0.25f;

    size_t fb = (size_t)bt * FEAT;
    feat[fb + c]       = hb[(size_t)t * H3];
    feat[fb + 256 + c] = f2bf(d1v[2]);
    feat[fb + 512 + c] = f2bf(d2);
}

// ---------------------------------------------------------------------------
// fp8 MFMA LSTM recurrence v4: grid (rq 0..7, dir 0..1) = 16 blocks, each
// owning 4 batch rows + full fp8 Whh register/AGPR-resident.
// KEY CHANGE vs v3: batch b sits at m-row 4b of the 16-row A-tile, so the
// D-fragment (row = quad*4 + r) has its valid row at r=0 in EVERY quad:
// all 64 lanes own (batch=quad, col) gate values in registers -> fully
// uniform epilogue, no D->LDS round trip, ONE barrier per step.
// h lives in an 8 KB fp8 A-fragment LDS double buffer:
//   hA byte addr = (ks>>1)*1024 + ((k>>3 & 3)*16 + m)*16 + (ks&1)*8 + (k&7)
//   (reader: lane reads 64 contiguous bytes at lane*16 per 1KB quarter ->
//    4 x ds_read_b128 per wave).
// Gate inputs come from the lane-packed gates3 layout (see k_gemm layout=1):
// one global dwordx4 per lane per step, issued before MFMA to hide latency.
// ---------------------------------------------------------------------------
__global__ __launch_bounds__(512, 2) void k_lstm_fp8(
    const unsigned short* __restrict__ g3f, const unsigned short* __restrict__ g3b,
    const unsigned char* __restrict__ wfrag8,
    const float* __restrict__ h0, const float* __restrict__ c0,
    const int* __restrict__ lens_sorted, float* __restrict__ out)
{
    int rq = blockIdx.x, dir = blockIdx.y;
    const unsigned short* g3 = (dir ? g3b : g3f) + (size_t)rq * 4194304;
    const unsigned char* wsrc = wfrag8 + (size_t)dir * 262144;

    __shared__ __align__(16) unsigned char hA[2][4096];

    int tid = threadIdx.x;
    int wave = tid >> 6, lane = tid & 63;
    int l16 = lane & 15, quad = lane >> 4;

    // full Whh resident: 64 x 8B per lane
    long long regB[4][2][8];
    {
        const long long* wsL = (const long long*)(const void*)wsrc;
        #pragma unroll
        for (int gb = 0; gb < 4; ++gb)
            #pragma unroll
            for (int uu = 0; uu < 2; ++uu)
                #pragma unroll
                for (int ks = 0; ks < 8; ++ks)
                    regB[gb][uu][ks] =
                        wsL[((size_t)((gb * 16 + 2 * wave + uu) * 8 + ks)) * 64 + lane];
    }

    // zero both hA buffers (rows != 4b stay zero forever)
    for (int i = tid; i < 2048; i += 512) ((unsigned int*)(void*)hA)[i] = 0;
    __syncthreads();
    // h0 -> hA[0] at m-row 4b
    for (int i = tid; i < 1024; i += 512) {
        int b = i >> 8, col = i & 255;
        float hv = h0[(size_t)dir * B_SZ * HH + (size_t)(rq * 4 + b) * HH + col];
        unsigned char byv = (unsigned char)(__builtin_amdgcn_cvt_pk_fp8_f32(hv, hv, 0, false) & 0xff);
        int addr = (col >> 6) * 1024 + (((col >> 3) & 3) * 16 + 4 * b) * 16
                 + ((col >> 5) & 1) * 8 + (col & 7);
        hA[0][addr] = byv;
    }

    int grow = rq * 4 + quad;            // this lane's batch row (batch = quad)
    int elen = lens_sorted[grow];
    int maxlen = lens_sorted[rq * 4];    // sorted desc -> first of quad is max
    int col0 = 32 * wave + l16, col1 = col0 + 16;
    float c2[2];
    c2[0] = c0[(size_t)dir * B_SZ * HH + (size_t)grow * HH + col0];
    c2[1] = c0[(size_t)dir * B_SZ * HH + (size_t)grow * HH + col1];
    float* out_r = out + (size_t)grow * T_SZ * 512 + dir * HH;
    const unsigned short* gbase = g3 + ((size_t)wave * 64 + l16 * 4 + quad) * 8;
    __syncthreads();

    for (int s = 0; s < maxlen; ++s) {
        // gate-input prefetch: ONE coalesced dwordx4 per lane (8 bf16: [uu][gb])
        uint4 gq = *(const uint4*)(const void*)(gbase + (size_t)s * 4096);

        // A-fragments: h(s-1), 4 x b128 per lane (64 contiguous bytes)
        const llong2* Ap = (const llong2*)(const void*)hA[s & 1];
        long long a_[8];
        #pragma unroll
        for (int r16 = 0; r16 < 4; ++r16) {
            llong2 p = Ap[r16 * 64 + lane];
            a_[2 * r16]     = p.x;
            a_[2 * r16 + 1] = p.y;
        }

        f32x4 acc[2][4];
        #pragma unroll
        for (int uu = 0; uu < 2; ++uu)
            #pragma unroll
            for (int gb = 0; gb < 4; ++gb) acc[uu][gb] = (f32x4){0.f, 0.f, 0.f, 0.f};

        #pragma unroll
        for (int ks = 0; ks < 8; ++ks)
            #pragma unroll
            for (int uu = 0; uu < 2; ++uu)
                #pragma unroll
                for (int gb = 0; gb < 4; ++gb)
                    acc[uu][gb] = __builtin_amdgcn_mfma_f32_16x16x32_fp8_fp8(
                        a_[ks], regB[gb][uu][ks], acc[uu][gb], 0, 0, 0);

        // uniform epilogue: every lane owns (batch=quad, col0/col1) at acc[..][..][0]
        unsigned char* hw = hA[(s + 1) & 1];
        #pragma unroll
        for (int uu = 0; uu < 2; ++uu) {
            unsigned int dA = uu ? gq.z : gq.x;   // [i, f] bf16 pair
            unsigned int dB = uu ? gq.w : gq.y;   // [g, o] bf16 pair
            float gi = acc[uu][0][0] + bf2f((unsigned short)(dA & 0xffffu));
            float gf = acc[uu][1][0] + bf2f((unsigned short)(dA >> 16));
            float gg = acc[uu][2][0] + bf2f((unsigned short)(dB & 0xffffu));
            float go = acc[uu][3][0] + bf2f((unsigned short)(dB >> 16));
            c2[uu] = sigm(gf) * c2[uu] + sigm(gi) * tanh_f(gg);
            float h = sigm(go) * tanh_f(c2[uu]);
            int col = uu ? col1 : col0;
            int addr = (col >> 6) * 1024 + (((col >> 3) & 3) * 16 + 4 * quad) * 16
                     + ((col >> 5) & 1) * 8 + (col & 7);
            hw[addr] = (unsigned char)(__builtin_amdgcn_cvt_pk_fp8_f32(h, h, 0, false) & 0xff);
            if (s < elen) {
                int t_out = dir ? (elen - 1 - s) : s;
                out_r[(size_t)t_out * 512 + col] = h;
            }
        }
        __syncthreads();
    }
}

// ---------------------------------------------------------------------------
// Workspace layout (bytes). gates_f overlaps dead a0/a1 regions.
// ---------------------------------------------------------------------------
#define OFF_XBF    ((size_t)0)
#define OFF_A0     ((size_t)5242880)
#define OFF_A1     ((size_t)38797312)
#define OFF_HBUF   ((size_t)72351744)
#define OFF_FEAT   ((size_t)89128960)
#define OFF_GF     OFF_A0                  /* 67,108,864 B over a0+a1 (dead) */
#define OFF_GB     ((size_t)139460608)
#define OFF_W0     ((size_t)206569472)
#define OFF_W1     ((size_t)206651392)
#define OFF_W2     ((size_t)207175680)
#define OFF_WIHF   ((size_t)207437824)
#define OFF_WIHB   ((size_t)209010688)
#define OFF_WFRAG  ((size_t)210583552)     /* 524288 B: fp8 Whh fragments f+b */
#define OFF_ORDER  ((size_t)212680704)
#define OFF_LENS   ((size_t)212680832)
#define OFF_ROWMAP ((size_t)212680960)

extern "C" void kernel_launch(void* const* d_in, const int* in_sizes, int n_in,
                              void* d_out, int out_size, void* d_ws, size_t ws_size,
                              hipStream_t stream)
{
    const float* x    = (const float*)d_in[0];
    const int*   xlen = (const int*)d_in[1];
    const float* eW0  = (const float*)d_in[2];
    const float* eb0  = (const float*)d_in[3];
    const float* eW1  = (const float*)d_in[4];
    const float* eb1  = (const float*)d_in[5];
    const float* eW2  = (const float*)d_in[6];
    const float* eb2  = (const float*)d_in[7];
    const float* Wihf = (const float*)d_in[8];
    const float* Whhf = (const float*)d_in[9];
    const float* bihf = (const float*)d_in[10];
    const float* bhhf = (const float*)d_in[11];
    const float* Wihb = (const float*)d_in[12];
    const float* Whhb = (const float*)d_in[13];
    const float* bihb = (const float*)d_in[14];
    const float* bhhb = (const float*)d_in[15];
    const float* h0   = (const float*)d_in[16];
    const float* c0   = (const float*)d_in[17];
    float* out = (float*)d_out;

    char* ws = (char*)d_ws;
    unsigned short* xbf    = (unsigned short*)(ws + OFF_XBF);
    unsigned short* a0     = (unsigned short*)(ws + OFF_A0);
    unsigned short* a1     = (unsigned short*)(ws + OFF_A1);
    unsigned short* hbuf   = (unsigned short*)(ws + OFF_HBUF);
    unsigned short* feat   = (unsigned short*)(ws + OFF_FEAT);
    unsigned short* gatesF = (unsigned short*)(ws + OFF_GF);
    unsigned short* gatesB = (unsigned short*)(ws + OFF_GB);
    unsigned short* w0     = (unsigned short*)(ws + OFF_W0);
    unsigned short* w1     = (unsigned short*)(ws + OFF_W1);
    unsigned short* w2     = (unsigned short*)(ws + OFF_W2);
    unsigned short* wihf   = (unsigned short*)(ws + OFF_WIHF);
    unsigned short* wihb   = (unsigned short*)(ws + OFF_WIHB);
    unsigned char*  wfrag8 = (unsigned char*)(ws + OFF_WFRAG);
    int* order             = (int*)(ws + OFF_ORDER);
    int* lens_sorted       = (int*)(ws + OFF_LENS);
    int* rowmap            = (int*)(ws + OFF_ROWMAP);

    // prep
    k_cvt<<<2048, 256, 0, stream>>>(x,    xbf,  B_SZ * T_SZ * DIN);
    k_cvt<<<160,  256, 0, stream>>>(eW0,  w0,   512 * 80);
    k_cvt<<<1024, 256, 0, stream>>>(eW1,  w1,   512 * 512);
    k_cvt<<<512,  256, 0, stream>>>(eW2,  w2,   256 * 512);
    k_cvt<<<2048, 256, 0, stream>>>(Wihf, wihf, 1024 * 768);
    k_cvt<<<2048, 256, 0, stream>>>(Wihb, wihb, 1024 * 768);
    k_wfrag8<<<128, 256, 0, stream>>>(Whhf, wfrag8);
    k_wfrag8<<<128, 256, 0, stream>>>(Whhb, wfrag8 + 262144);
    k_order<<<1, 64, 0, stream>>>(xlen, order, lens_sorted, out + (size_t)B_SZ * T_SZ * 512);
    k_rowmap<<<128, 256, 0, stream>>>(lens_sorted, rowmap);
    k_ztail<<<dim3(T_SZ, B_SZ), 128, 0, stream>>>(lens_sorted, out);

    // encoder: 80 -> 512 -> 512 -> 256, ReLU each layer (row-major stores)
    k_gemm<<<dim3(1024, 4), 256, 0, stream>>>(xbf, w0, nullptr, eb0, nullptr, a0,   32768, 512, 80,  1, 0);
    k_gemm<<<dim3(1024, 4), 256, 0, stream>>>(a0,  w1, nullptr, eb1, nullptr, a1,   32768, 512, 512, 1, 0);
    k_gemm<<<dim3(1024, 2), 256, 0, stream>>>(a1,  w2, nullptr, eb2, nullptr, hbuf, 32768, 256, 512, 1, 0);

    // delta features + sort reorder -> feat[bs,t,768]
    k_deltas<<<32768, 256, 0, stream>>>(hbuf, order, feat);

    // gate inputs: feat @ Wih^T + (b_ih + b_hh), stored in LSTM lane-packed layout
    k_gemm<<<dim3(1024, 8), 256, 0, stream>>>(feat, wihf, nullptr, bihf, bhhf, gatesF, 32768, 1024, 768, 0, 1);
    k_gemm<<<dim3(1024, 8), 256, 0, stream>>>(feat, wihb, rowmap,  bihb, bhhb, gatesB, 32768, 1024, 768, 0, 1);

    // fp8 recurrence: 16 independent blocks (2 dirs x 8 batch quads), no sync
    k_lstm_fp8<<<dim3(8, 2), 512, 0, stream>>>(gatesF, gatesB, wfrag8, h0, c0,
                                               lens_sorted, out);
}

// Round 6
// 2457.377 us; speedup vs baseline: 11.1479x; 1.1181x over previous
//
#include <hip/hip_runtime.h>
#include <cstdint>
#include <cstddef>

// ---------------------------------------------------------------------------
// Problem constants
// ---------------------------------------------------------------------------
#define B_SZ 32
#define T_SZ 1024
#define DIN  80
#define H3   256   // encoder output dim
#define FEAT 768   // 3 * H3
#define G4   1024  // 4 * H (LSTM gates)
#define HH   256   // LSTM hidden

typedef __attribute__((ext_vector_type(8))) short short8;   // 8 x bf16 (4 VGPRs)
typedef __attribute__((ext_vector_type(4))) float f32x4;    // MFMA accumulator
typedef __attribute__((ext_vector_type(8))) int v8i;        // 32B fp8 fragment

__device__ inline float bf2f(unsigned short u) {
    return __uint_as_float(((unsigned int)u) << 16);
}
__device__ inline unsigned short f2bf(float f) {
    unsigned int u = __float_as_uint(f);
    u += 0x7fffu + ((u >> 16) & 1u);   // RNE
    return (unsigned short)(u >> 16);
}
// fast sigmoid/tanh: v_exp (exp2) + v_rcp
#define LOG2E 1.4426950408889634f
__device__ inline float sigm(float x) {
    return __builtin_amdgcn_rcpf(1.f + __builtin_amdgcn_exp2f(x * -LOG2E));
}
__device__ inline float tanh_f(float x) {
    return fmaf(2.f, __builtin_amdgcn_rcpf(1.f + __builtin_amdgcn_exp2f(x * (-2.f * LOG2E))), -1.f);
}

// ---------------------------------------------------------------------------
// fp32 -> bf16 conversion (grid-stride)
// ---------------------------------------------------------------------------
__global__ void k_cvt(const float* __restrict__ src, unsigned short* __restrict__ dst, int n) {
    int i = blockIdx.x * blockDim.x + threadIdx.x;
    int stride = gridDim.x * blockDim.x;
    for (; i < n; i += stride) dst[i] = f2bf(src[i]);
}

// ---------------------------------------------------------------------------
// stable argsort by descending length (matches jnp.argsort(-lens), stable)
// ---------------------------------------------------------------------------
__global__ void k_order(const int* __restrict__ lens, int* __restrict__ order,
                        int* __restrict__ lens_sorted, float* __restrict__ out_order) {
    int b = threadIdx.x;
    if (b < B_SZ) {
        int lb = lens[b];
        int r = 0;
        for (int j = 0; j < B_SZ; ++j) {
            int lj = lens[j];
            if (lj > lb || (lj == lb && j < b)) ++r;
        }
        order[r] = b;
        lens_sorted[r] = lb;
        out_order[r] = (float)b;   // second tuple output, as float
    }
}

// rowmap for backward direction: rowmap[bs*1024+t] = bs*1024 + clip(len-1-t, 0, 1023)
__global__ void k_rowmap(const int* __restrict__ lens_sorted, int* __restrict__ rowmap) {
    int idx = blockIdx.x * 256 + threadIdx.x;   // 32768 total
    int bs = idx >> 10, t = idx & 1023;
    int len = lens_sorted[bs];
    int src = len - 1 - t;
    src = src < 0 ? 0 : src;
    rowmap[idx] = (bs << 10) + src;
}

// zero the padded tail: out[bs, t, 0:512] = 0 for t >= len[bs]
__global__ void k_ztail(const int* __restrict__ lens_sorted, float* __restrict__ out) {
    int t = blockIdx.x, bs = blockIdx.y;
    if (t < lens_sorted[bs]) return;
    float4* p = (float4*)(out + ((size_t)bs * T_SZ + t) * 512);
    p[threadIdx.x] = make_float4(0.f, 0.f, 0.f, 0.f);   // 128 threads x 16B
}

// ---------------------------------------------------------------------------
// Whh [1024 rows (n), 256 cols (k)] fp32 -> fp8 e4m3 in MFMA B-fragment order
// for mfma_scale_f32_16x16x128_f8f6f4: per (ntile, kchunk) slot of 64 lanes x
// 32 bytes: n = ntile*16 + (lane&15), k = kchunk*128 + (lane>>4)*32 + j,
// j = 0..31 contiguous. slot = (ntile*2 + kchunk); byte addr = (slot*64 +
// lane)*32. One thread per 16-byte half (16384 threads per direction).
// ---------------------------------------------------------------------------
__global__ void k_wfrag8(const float* __restrict__ Whh, unsigned char* __restrict__ dst) {
    int t = blockIdx.x * 256 + threadIdx.x;   // 0..16383
    int lane = t & 63, hf = (t >> 6) & 1, kc = (t >> 7) & 1, nt = t >> 8;
    int n = nt * 16 + (lane & 15);
    int k0 = kc * 128 + (lane >> 4) * 32 + hf * 16;
    const float* p = Whh + (size_t)n * 256 + k0;
    unsigned int o[4];
    #pragma unroll
    for (int q = 0; q < 4; ++q) {
        float4 f = *(const float4*)(const void*)(p + 4 * q);
        o[q] = (__builtin_amdgcn_cvt_pk_fp8_f32(f.x, f.y, 0, false) & 0xffff)
             | (__builtin_amdgcn_cvt_pk_fp8_f32(f.z, f.w, 0, false) << 16);
    }
    int slot = (nt * 2 + kc) * 64 + lane;
    *(uint4*)(void*)(dst + (size_t)slot * 32 + hf * 16) = make_uint4(o[0], o[1], o[2], o[3]);
}

// ---------------------------------------------------------------------------
// bf16 MFMA GEMM: C[M,N] = act(A[M,K] @ Bw[N,K]^T + bias1 + bias2), bf16 out.
// Block tile 32(M) x 128(N), 4 waves (2x2), each wave 16x64 via 4 accums.
// layout=0: row-major C[M,N].
// layout=1: LSTM gate layout (per rq buffer of 4 Mi bf16):
//   idx = rq*4194304 + ((t*8 + w)*64 + l16c*4 + b4)*8 + uu*4 + gb
//   (one dwordx4 per LSTM lane per step).
// ---------------------------------------------------------------------------
__global__ __launch_bounds__(256) void k_gemm(
    const unsigned short* __restrict__ A, const unsigned short* __restrict__ Bw,
    const int* __restrict__ rowmap,
    const float* __restrict__ bias1, const float* __restrict__ bias2,
    unsigned short* __restrict__ C, int M, int N, int K, int relu, int layout)
{
    int tid  = threadIdx.x;
    int lane = tid & 63;
    int wave = tid >> 6;
    int waveM = wave >> 1, waveN = wave & 1;
    int l16  = lane & 15;
    int quad = lane >> 4;
    int mBase = blockIdx.x * 32 + waveM * 16;
    int nBase = blockIdx.y * 128 + waveN * 64;

    int mA = mBase + l16;
    int rowA = rowmap ? rowmap[mA] : mA;
    const unsigned short* pA  = A  + (size_t)rowA * K + quad * 8;
    const unsigned short* pB0 = Bw + (size_t)(nBase +  0 + l16) * K + quad * 8;
    const unsigned short* pB1 = Bw + (size_t)(nBase + 16 + l16) * K + quad * 8;
    const unsigned short* pB2 = Bw + (size_t)(nBase + 32 + l16) * K + quad * 8;
    const unsigned short* pB3 = Bw + (size_t)(nBase + 48 + l16) * K + quad * 8;

    const short8 z8 = {0, 0, 0, 0, 0, 0, 0, 0};
    f32x4 acc0 = {0.f, 0.f, 0.f, 0.f};
    f32x4 acc1 = acc0, acc2 = acc0, acc3 = acc0;

    for (int k0 = 0; k0 < K; k0 += 32) {
        bool ok = (k0 + quad * 8) < K;
        short8 av  = ok ? *(const short8*)(const void*)(pA  + k0) : z8;
        short8 bv0 = ok ? *(const short8*)(const void*)(pB0 + k0) : z8;
        short8 bv1 = ok ? *(const short8*)(const void*)(pB1 + k0) : z8;
        short8 bv2 = ok ? *(const short8*)(const void*)(pB2 + k0) : z8;
        short8 bv3 = ok ? *(const short8*)(const void*)(pB3 + k0) : z8;
        acc0 = __builtin_amdgcn_mfma_f32_16x16x32_bf16(av, bv0, acc0, 0, 0, 0);
        acc1 = __builtin_amdgcn_mfma_f32_16x16x32_bf16(av, bv1, acc1, 0, 0, 0);
        acc2 = __builtin_amdgcn_mfma_f32_16x16x32_bf16(av, bv2, acc2, 0, 0, 0);
        acc3 = __builtin_amdgcn_mfma_f32_16x16x32_bf16(av, bv3, acc3, 0, 0, 0);
    }

    int rowD = mBase + quad * 4;
    #pragma unroll
    for (int nt = 0; nt < 4; ++nt) {
        int col = nBase + nt * 16 + l16;
        float bsum = 0.f;
        if (bias1) bsum += bias1[col];
        if (bias2) bsum += bias2[col];
        f32x4 a = (nt == 0) ? acc0 : (nt == 1) ? acc1 : (nt == 2) ? acc2 : acc3;
        #pragma unroll
        for (int r = 0; r < 4; ++r) {
            float v = a[r] + bsum;
            if (relu) v = v > 0.f ? v : 0.f;
            if (layout == 0) {
                C[(size_t)(rowD + r) * N + col] = f2bf(v);
            } else {
                int row = rowD + r;
                int bs = row >> 10, t = row & 1023;
                int rq = bs >> 2, b4 = bs & 3;
                int gb = col >> 8, cu = (col >> 4) & 15, l16c = col & 15;
                int w = cu >> 1, uu = cu & 1;
                size_t idx = (size_t)rq * 4194304
                           + ((size_t)(t * 8 + w) * 64 + l16c * 4 + b4) * 8 + uu * 4 + gb;
                C[idx] = f2bf(v);
            }
        }
    }
}

// ---------------------------------------------------------------------------
// delta features + batch reorder (unchanged)
// ---------------------------------------------------------------------------
__global__ void k_deltas(const unsigned short* __restrict__ hbuf, const int* __restrict__ order,
                         unsigned short* __restrict__ feat)
{
    int bt = blockIdx.x;        // bs*1024 + t
    int c  = threadIdx.x;       // 0..255
    int bs = bt >> 10, t = bt & 1023;
    int b  = order[bs];
    const unsigned short* hb = hbuf + (size_t)b * T_SZ * H3 + c;

    float hv[9];
    #pragma unroll
    for (int d = -4; d <= 4; ++d) {
        int tt = t + d;
        tt = tt < 0 ? 0 : (tt > T_SZ - 1 ? T_SZ - 1 : tt);
        hv[d + 4] = bf2f(hb[(size_t)tt * H3]);
    }
    float d1v[5];
    #pragma unroll
    for (int s = -2; s <= 2; ++s) {
        d1v[s + 2] = (hv[s + 5] - hv[s + 3]) * 0.5f + (hv[s + 6] - hv[s + 2]) * 0.25f;
    }
    int sp1 = (t + 1 > T_SZ - 1 ? T_SZ - 1 : t + 1) - t;
    int sm1 = (t - 1 < 0 ? 0 : t - 1) - t;
    int sp2 = (t + 2 > T_SZ - 1 ? T_SZ - 1 : t + 2) - t;
    int sm2 = (t - 2 < 0 ? 0 : t - 2) - t;
    float d2 = (d1v[2 + sp1] - d1v[2 + sm1]) * 0.5f + (d1v[2 + sp2] - d1v[2 + sm2]) * 0.25f;

    size_t fb = (size_t)bt * FEAT;
    feat[fb + c]       = hb[(size_t)t * H3];
    feat[fb + 256 + c] = f2bf(d1v[2]);
    feat[fb + 512 + c] = f2bf(d2);
}

// ---------------------------------------------------------------------------
// fp8 MX-MFMA LSTM recurrence v5: grid (rq 0..7, dir 0..1) = 16 blocks,
// 4 batch rows/block (batch b at m-row 4b -> valid D row in every quad),
// full Whh register/AGPR-resident as K=128 fragments (16 x v8i = 128 VGPRs).
// KEY CHANGE vs v4: mfma_scale_f32_16x16x128_f8f6f4 with unit scales
// (E8M0 0x7F = x1.0): 128 MFMAs/block-step instead of 512 at 2x the rate
// -> MFMA cycles/step ~2483 -> ~1105.
// h in LDS as linear per-lane 32B A-chunks: chunk(m, kq) at
// kc*2048 + (kq*16 + m)*32, reader lane l reads [lane*32, +32) per kc.
// One barrier per step; gate inputs via lane-packed g3 (one dwordx4/lane).
// ---------------------------------------------------------------------------
__global__ __launch_bounds__(512, 2) void k_lstm_fp8(
    const unsigned short* __restrict__ g3f, const unsigned short* __restrict__ g3b,
    const unsigned char* __restrict__ wfrag8,
    const float* __restrict__ h0, const float* __restrict__ c0,
    const int* __restrict__ lens_sorted, float* __restrict__ out)
{
    int rq = blockIdx.x, dir = blockIdx.y;
    const unsigned short* g3 = (dir ? g3b : g3f) + (size_t)rq * 4194304;
    const unsigned char* wsrc = wfrag8 + (size_t)dir * 262144;

    __shared__ __align__(16) unsigned char hA[2][4096];

    int tid = threadIdx.x;
    int wave = tid >> 6, lane = tid & 63;
    int l16 = lane & 15, quad = lane >> 4;

    // full Whh resident: 16 x 32B per lane. regB[gb][p][kc]:
    // gb = gate block, p = col pair (cols 32w+l16 / +16), kc = K chunk.
    v8i regB[4][2][2];
    #pragma unroll
    for (int gb = 0; gb < 4; ++gb)
        #pragma unroll
        for (int p = 0; p < 2; ++p)
            #pragma unroll
            for (int kc = 0; kc < 2; ++kc) {
                int nt = gb * 16 + 2 * wave + p;
                regB[gb][p][kc] = *(const v8i*)(const void*)
                    (wsrc + ((size_t)((nt * 2 + kc) * 64 + lane)) * 32);
            }

    // zero both hA buffers (m-rows != 4b stay zero forever; fp8 0x00 == 0.0)
    for (int i = tid; i < 2048; i += 512) ((unsigned int*)(void*)hA)[i] = 0;
    __syncthreads();
    // h0 -> hA[0] at m-row 4b: byte(m,k) at (k>>7)*2048 + (((k>>5)&3)*16+m)*32 + (k&31)
    for (int i = tid; i < 1024; i += 512) {
        int b = i >> 8, c = i & 255;
        float hv = h0[(size_t)dir * B_SZ * HH + (size_t)(rq * 4 + b) * HH + c];
        hA[0][(c >> 7) * 2048 + (((c >> 5) & 3) * 16 + 4 * b) * 32 + (c & 31)] =
            (unsigned char)(__builtin_amdgcn_cvt_pk_fp8_f32(hv, hv, 0, false) & 0xff);
    }

    int grow = rq * 4 + quad;            // this lane's batch row (batch = quad)
    int elen = lens_sorted[grow];
    int maxlen = lens_sorted[rq * 4];    // sorted desc -> first of quad is max
    int col0 = 32 * wave + l16, col1 = col0 + 16;
    float c2[2];
    c2[0] = c0[(size_t)dir * B_SZ * HH + (size_t)grow * HH + col0];
    c2[1] = c0[(size_t)dir * B_SZ * HH + (size_t)grow * HH + col1];
    float* out_r = out + (size_t)grow * T_SZ * 512 + dir * HH;
    const unsigned short* gbase = g3 + ((size_t)wave * 64 + l16 * 4 + quad) * 8;
    __syncthreads();

    for (int s = 0; s < maxlen; ++s) {
        // gate-input prefetch: ONE coalesced dwordx4 per lane (8 bf16: [p][gb])
        uint4 gq = *(const uint4*)(const void*)(gbase + (size_t)s * 4096);

        // A-fragments: h(s-1), 32B per K-chunk per lane, contiguous
        const unsigned char* Ab = hA[s & 1];
        v8i a0 = *(const v8i*)(const void*)(Ab + lane * 32);
        v8i a1 = *(const v8i*)(const void*)(Ab + 2048 + lane * 32);

        f32x4 acc[2][4];
        #pragma unroll
        for (int p = 0; p < 2; ++p)
            #pragma unroll
            for (int gb = 0; gb < 4; ++gb) acc[p][gb] = (f32x4){0.f, 0.f, 0.f, 0.f};

        #pragma unroll
        for (int p = 0; p < 2; ++p)
            #pragma unroll
            for (int gb = 0; gb < 4; ++gb) {
                acc[p][gb] = __builtin_amdgcn_mfma_scale_f32_16x16x128_f8f6f4(
                    a0, regB[gb][p][0], acc[p][gb], 0, 0,
                    0, 0x7F7F7F7F, 0, 0x7F7F7F7F);
                acc[p][gb] = __builtin_amdgcn_mfma_scale_f32_16x16x128_f8f6f4(
                    a1, regB[gb][p][1], acc[p][gb], 0, 0,
                    0, 0x7F7F7F7F, 0, 0x7F7F7F7F);
            }

        // uniform epilogue: every lane owns (batch=quad, col0/col1) at acc[p][gb][0]
        unsigned char* hw = hA[(s + 1) & 1];
        #pragma unroll
        for (int p = 0; p < 2; ++p) {
            unsigned int dA = p ? gq.z : gq.x;   // [i, f] bf16 pair
            unsigned int dB = p ? gq.w : gq.y;   // [g, o] bf16 pair
            float gi = acc[p][0][0] + bf2f((unsigned short)(dA & 0xffffu));
            float gf = acc[p][1][0] + bf2f((unsigned short)(dA >> 16));
            float gg = acc[p][2][0] + bf2f((unsigned short)(dB & 0xffffu));
            float go = acc[p][3][0] + bf2f((unsigned short)(dB >> 16));
            c2[p] = sigm(gf) * c2[p] + sigm(gi) * tanh_f(gg);
            float h = sigm(go) * tanh_f(c2[p]);
            int col = p ? col1 : col0;
            hw[(col >> 7) * 2048 + (((col >> 5) & 3) * 16 + 4 * quad) * 32 + (col & 31)] =
                (unsigned char)(__builtin_amdgcn_cvt_pk_fp8_f32(h, h, 0, false) & 0xff);
            if (s < elen) {
                int t_out = dir ? (elen - 1 - s) : s;
                out_r[(size_t)t_out * 512 + col] = h;
            }
        }
        __syncthreads();
    }
}

// ---------------------------------------------------------------------------
// Workspace layout (bytes). gates_f overlaps dead a0/a1 regions.
// ---------------------------------------------------------------------------
#define OFF_XBF    ((size_t)0)
#define OFF_A0     ((size_t)5242880)
#define OFF_A1     ((size_t)38797312)
#define OFF_HBUF   ((size_t)72351744)
#define OFF_FEAT   ((size_t)89128960)
#define OFF_GF     OFF_A0                  /* 67,108,864 B over a0+a1 (dead) */
#define OFF_GB     ((size_t)139460608)
#define OFF_W0     ((size_t)206569472)
#define OFF_W1     ((size_t)206651392)
#define OFF_W2     ((size_t)207175680)
#define OFF_WIHF   ((size_t)207437824)
#define OFF_WIHB   ((size_t)209010688)
#define OFF_WFRAG  ((size_t)210583552)     /* 524288 B: fp8 Whh fragments f+b */
#define OFF_ORDER  ((size_t)212680704)
#define OFF_LENS   ((size_t)212680832)
#define OFF_ROWMAP ((size_t)212680960)

extern "C" void kernel_launch(void* const* d_in, const int* in_sizes, int n_in,
                              void* d_out, int out_size, void* d_ws, size_t ws_size,
                              hipStream_t stream)
{
    const float* x    = (const float*)d_in[0];
    const int*   xlen = (const int*)d_in[1];
    const float* eW0  = (const float*)d_in[2];
    const float* eb0  = (const float*)d_in[3];
    const float* eW1  = (const float*)d_in[4];
    const float* eb1  = (const float*)d_in[5];
    const float* eW2  = (const float*)d_in[6];
    const float* eb2  = (const float*)d_in[7];
    const float* Wihf = (const float*)d_in[8];
    const float* Whhf = (const float*)d_in[9];
    const float* bihf = (const float*)d_in[10];
    const float* bhhf = (const float*)d_in[11];
    const float* Wihb = (const float*)d_in[12];
    const float* Whhb = (const float*)d_in[13];
    const float* bihb = (const float*)d_in[14];
    const float* bhhb = (const float*)d_in[15];
    const float* h0   = (const float*)d_in[16];
    const float* c0   = (const float*)d_in[17];
    float* out = (float*)d_out;

    char* ws = (char*)d_ws;
    unsigned short* xbf    = (unsigned short*)(ws + OFF_XBF);
    unsigned short* a0     = (unsigned short*)(ws + OFF_A0);
    unsigned short* a1     = (unsigned short*)(ws + OFF_A1);
    unsigned short* hbuf   = (unsigned short*)(ws + OFF_HBUF);
    unsigned short* feat   = (unsigned short*)(ws + OFF_FEAT);
    unsigned short* gatesF = (unsigned short*)(ws + OFF_GF);
    unsigned short* gatesB = (unsigned short*)(ws + OFF_GB);
    unsigned short* w0     = (unsigned short*)(ws + OFF_W0);
    unsigned short* w1     = (unsigned short*)(ws + OFF_W1);
    unsigned short* w2     = (unsigned short*)(ws + OFF_W2);
    unsigned short* wihf   = (unsigned short*)(ws + OFF_WIHF);
    unsigned short* wihb   = (unsigned short*)(ws + OFF_WIHB);
    unsigned char*  wfrag8 = (unsigned char*)(ws + OFF_WFRAG);
    int* order             = (int*)(ws + OFF_ORDER);
    int* lens_sorted       = (int*)(ws + OFF_LENS);
    int* rowmap            = (int*)(ws + OFF_ROWMAP);

    // prep
    k_cvt<<<2048, 256, 0, stream>>>(x,    xbf,  B_SZ * T_SZ * DIN);
    k_cvt<<<160,  256, 0, stream>>>(eW0,  w0,   512 * 80);
    k_cvt<<<1024, 256, 0, stream>>>(eW1,  w1,   512 * 512);
    k_cvt<<<512,  256, 0, stream>>>(eW2,  w2,   256 * 512);
    k_cvt<<<2048, 256, 0, stream>>>(Wihf, wihf, 1024 * 768);
    k_cvt<<<2048, 256, 0, stream>>>(Wihb, wihb, 1024 * 768);
    k_wfrag8<<<64, 256, 0, stream>>>(Whhf, wfrag8);
    k_wfrag8<<<64, 256, 0, stream>>>(Whhb, wfrag8 + 262144);
    k_order<<<1, 64, 0, stream>>>(xlen, order, lens_sorted, out + (size_t)B_SZ * T_SZ * 512);
    k_rowmap<<<128, 256, 0, stream>>>(lens_sorted, rowmap);
    k_ztail<<<dim3(T_SZ, B_SZ), 128, 0, stream>>>(lens_sorted, out);

    // encoder: 80 -> 512 -> 512 -> 256, ReLU each layer (row-major stores)
    k_gemm<<<dim3(1024, 4), 256, 0, stream>>>(xbf, w0, nullptr, eb0, nullptr, a0,   32768, 512, 80,  1, 0);
    k_gemm<<<dim3(1024, 4), 256, 0, stream>>>(a0,  w1, nullptr, eb1, nullptr, a1,   32768, 512, 512, 1, 0);
    k_gemm<<<dim3(1024, 2), 256, 0, stream>>>(a1,  w2, nullptr, eb2, nullptr, hbuf, 32768, 256, 512, 1, 0);

    // delta features + sort reorder -> feat[bs,t,768]
    k_deltas<<<32768, 256, 0, stream>>>(hbuf, order, feat);

    // gate inputs: feat @ Wih^T + (b_ih + b_hh), stored in LSTM lane-packed layout
    k_gemm<<<dim3(1024, 8), 256, 0, stream>>>(feat, wihf, nullptr, bihf, bhhf, gatesF, 32768, 1024, 768, 0, 1);
    k_gemm<<<dim3(1024, 8), 256, 0, stream>>>(feat, wihb, rowmap,  bihb, bhhb, gatesB, 32768, 1024, 768, 0, 1);

    // fp8 MX recurrence: 16 independent blocks (2 dirs x 8 batch quads), no sync
    k_lstm_fp8<<<dim3(8, 2), 512, 0, stream>>>(gatesF, gatesB, wfrag8, h0, c0,
                                               lens_sorted, out);
}